// Round 12
// baseline (370.208 us; speedup 1.0000x reference)
//
#include <hip/hip_runtime.h>
#include <hip/hip_bf16.h>

#define DEVI __device__ __forceinline__

typedef __attribute__((ext_vector_type(8))) short short8v;   // 8 bf16
typedef __attribute__((ext_vector_type(4))) short short4v;   // 4 bf16
typedef __attribute__((ext_vector_type(4))) float float4v;
typedef __attribute__((ext_vector_type(16))) float f32x16;

#if defined(__has_builtin)
#if __has_builtin(__builtin_amdgcn_exp2f)
#define EXP2F(x) __builtin_amdgcn_exp2f(x)
#endif
#endif
#ifndef EXP2F
#define EXP2F(x) exp2f(x)
#endif

constexpr int Mm = 2, Bb = 8, Tt = 1024, Cc = 512, Hh = 8, HSs = 64;
constexpr int ROWS = Bb * Tt;                 // 8192 tokens per modality
constexpr size_t BTC = (size_t)Bb * Tt * Cc;  // f32 elems per modality tensor
constexpr size_t SLAB = (size_t)ROWS * 512;   // bf16 elems per modality slab
constexpr size_t KOFF = (size_t)2 * ROWS * 768;   // K region inside Fb
constexpr float SCQ = 0.18033688011112042f;       // 0.125 * log2(e)

DEVI short f2bf(float f) {
    __hip_bfloat16 h = __float2bfloat16(f);
    short s; __builtin_memcpy(&s, &h, 2); return s;
}
DEVI float bf2f(short s) {
    unsigned u = ((unsigned)(unsigned short)s) << 16;
    float f; __builtin_memcpy(&f, &u, 4); return f;
}

DEVI float4v mfma16(short8v a, short8v b, float4v c) {
    return __builtin_amdgcn_mfma_f32_16x16x32_bf16(a, b, c, 0, 0, 0);
}
DEVI f32x16 mfma32(short8v a, short8v b, f32x16 c) {
    return __builtin_amdgcn_mfma_f32_32x32x16_bf16(a, b, c, 0, 0, 0);
}

DEVI void gload_lds16(const short* g, short* l) {
    __builtin_amdgcn_global_load_lds(
        (const __attribute__((address_space(1))) void*)g,
        (__attribute__((address_space(3))) void*)l, 16, 0, 0);
}

// ---------------------------------------------------------------- mega transpose+convert
struct TDesc {
    const float* src; short* dst;
    int K, N;
    long long moff, hoff;
    int base;
};
struct TPack { TDesc d[14]; };

__global__ __launch_bounds__(256) void transpose_all(TPack p) {
    __shared__ float t[32][33];
    int bid = blockIdx.x;
    int di = 0;
#pragma unroll
    for (int i = 1; i < 14; i++) if (bid >= p.d[i].base) di = i;
    TDesc d = p.d[di];
    int local = bid - d.base;
    int kb = d.K >> 5, nb = d.N >> 5;
    int bx = local % kb; int rest = local / kb;
    int by = rest % nb;  int z = rest / nb;
    int k0 = bx * 32, n0 = by * 32;
    size_t so = (size_t)z * d.K * d.N;
    short* dst = d.dst + (size_t)(z >> 3) * d.moff + (size_t)(z & 7) * d.hoff;
    int tx = threadIdx.x & 31, ty = threadIdx.x >> 5;
#pragma unroll
    for (int i = 0; i < 32; i += 8)
        t[ty + i][tx] = d.src[so + (size_t)(k0 + ty + i) * d.N + n0 + tx];
    __syncthreads();
#pragma unroll
    for (int i = 0; i < 32; i += 8)
        dst[(size_t)(n0 + ty + i) * d.K + k0 + tx] = f2bf(t[tx][ty + i]);
}

// concat q/k/v biases (each (M,256) f32) -> (M, 768)
__global__ __launch_bounds__(256) void bias_cat3(const float* __restrict__ q,
                                                 const float* __restrict__ k,
                                                 const float* __restrict__ v,
                                                 float* __restrict__ o) {
    int m = blockIdx.x, t = threadIdx.x;
    o[m * 768 + t]       = q[m * 256 + t];
    o[m * 768 + 256 + t] = k[m * 256 + t];
    o[m * 768 + 512 + t] = v[m * 256 + t];
}

// ---------------------------------------------------------------- layernorm: f32 in, 1 wave/row
__global__ __launch_bounds__(256) void ln_kernel(const float* __restrict__ x,
                                                 const float* __restrict__ g,
                                                 const float* __restrict__ b,
                                                 short* __restrict__ out, size_t xzs) {
    int z = blockIdx.y;
    x += z * xzs; g += z * Cc; b += z * Cc; out += z * SLAB;
    int row = blockIdx.x * 4 + (threadIdx.x >> 6);
    int l = threadIdx.x & 63;
    const float* xr = x + (size_t)row * Cc;
    float4 a = *(const float4*)&xr[l * 4];
    float4 c = *(const float4*)&xr[256 + l * 4];
    float s = (a.x + a.y) + (a.z + a.w) + (c.x + c.y) + (c.z + c.w);
    float q = (a.x * a.x + a.y * a.y) + (a.z * a.z + a.w * a.w) +
              (c.x * c.x + c.y * c.y) + (c.z * c.z + c.w * c.w);
#pragma unroll
    for (int o = 1; o < 64; o <<= 1) { s += __shfl_xor(s, o, 64); q += __shfl_xor(q, o, 64); }
    float mu = s * (1.f / Cc);
    float var = q * (1.f / Cc) - mu * mu;
    float rs = rsqrtf(var + 1e-5f);
    float4 ga = *(const float4*)&g[l * 4],   gc = *(const float4*)&g[256 + l * 4];
    float4 ba = *(const float4*)&b[l * 4],   bc = *(const float4*)&b[256 + l * 4];
    short4v o1, o2;
    o1[0] = f2bf((a.x - mu) * rs * ga.x + ba.x);
    o1[1] = f2bf((a.y - mu) * rs * ga.y + ba.y);
    o1[2] = f2bf((a.z - mu) * rs * ga.z + ba.z);
    o1[3] = f2bf((a.w - mu) * rs * ga.w + ba.w);
    o2[0] = f2bf((c.x - mu) * rs * gc.x + bc.x);
    o2[1] = f2bf((c.y - mu) * rs * gc.y + bc.y);
    o2[2] = f2bf((c.z - mu) * rs * gc.z + bc.z);
    o2[3] = f2bf((c.w - mu) * rs * gc.w + bc.w);
    short* orow = out + (size_t)row * Cc;
    *(short4v*)&orow[l * 4]       = o1;
    *(short4v*)&orow[256 + l * 4] = o2;
}

// ---------------------------------------------------------------- layernorm: bf16 in, 1 wave/row
__global__ __launch_bounds__(256) void ln_bf(const short* __restrict__ x,
                                             const float* __restrict__ g,
                                             const float* __restrict__ b,
                                             short* __restrict__ out) {
    int z = blockIdx.y;
    x += z * SLAB; g += z * Cc; b += z * Cc; out += z * SLAB;
    int row = blockIdx.x * 4 + (threadIdx.x >> 6);
    int l = threadIdx.x & 63;
    const short* xr = x + (size_t)row * Cc;
    short8v v = *(const short8v*)&xr[l * 8];
    float xv[8];
    float s = 0.f, q = 0.f;
#pragma unroll
    for (int i = 0; i < 8; i++) {
        xv[i] = bf2f(v[i]);
        s += xv[i]; q += xv[i] * xv[i];
    }
#pragma unroll
    for (int o = 1; o < 64; o <<= 1) { s += __shfl_xor(s, o, 64); q += __shfl_xor(q, o, 64); }
    float mu = s * (1.f / Cc);
    float var = q * (1.f / Cc) - mu * mu;
    float rs = rsqrtf(var + 1e-5f);
    short8v ov;
#pragma unroll
    for (int i = 0; i < 8; i++) {
        float gg = g[l * 8 + i], bb = b[l * 8 + i];
        ov[i] = f2bf((xv[i] - mu) * rs * gg + bb);
    }
    *(short8v*)&out[(size_t)row * Cc + l * 8] = ov;
}

// ---------------------------------------------------------------- m97-style GEMM, z-batched
template<int BM, int BN, int ACT, bool BIAS, bool RES, bool WF, bool WB>
__global__ __launch_bounds__(256, 2) void gemm2(
    const short* __restrict__ A, int lda, long long a_zs,
    const short* __restrict__ Wt, int ldw, long long w_zs,
    const float* __restrict__ bias, long long bias_zs,
    const float* __restrict__ res, long long res_zs,
    float* __restrict__ outF, long long outF_zs,
    short* __restrict__ outB, long long outB_zs,
    int ldc, int K, float oscale) {
    constexpr int BK = 64;
    __shared__ short As[BM][BK];
    __shared__ short Bs[BN][BK];
    long long z = blockIdx.z;
    A += z * a_zs; Wt += z * w_zs;
    if (BIAS) bias += z * bias_zs;
    if (RES)  res  += z * res_zs;
    if (WF)   outF += z * outF_zs;
    if (WB)   outB += z * outB_zs;
    int m0 = blockIdx.x * BM, n0 = blockIdx.y * BN;
    int tid = threadIdx.x, wv = tid >> 6, l = tid & 63, lr = l & 15, lg = l >> 4;
    constexpr int WM = BM / 2, WN = BN / 2;
    int wm = wv & 1, wn = wv >> 1;
    constexpr int AI = WM / 16, BJ = WN / 16;
    float4v acc[AI][BJ] = {};
    int lrow = l >> 3;
    int gcol = (l & 7) ^ lrow;
    constexpr int CHA = BM / 8, CHB = BN / 8;
    for (int k0 = 0; k0 < K; k0 += BK) {
        __syncthreads();
#pragma unroll
        for (int c = 0; c < CHA / 4; c++) {
            int ch = wv + c * 4;
            gload_lds16(&A[(size_t)(m0 + ch * 8 + lrow) * lda + k0 + gcol * 8],
                        &As[ch * 8][0]);
        }
#pragma unroll
        for (int c = 0; c < CHB / 4; c++) {
            int ch = wv + c * 4;
            gload_lds16(&Wt[(size_t)(n0 + ch * 8 + lrow) * ldw + k0 + gcol * 8],
                        &Bs[ch * 8][0]);
        }
        __syncthreads();
#pragma unroll
        for (int kk = 0; kk < 2; kk++) {
            int g = (kk * 4 + lg) ^ (lr & 7);
            short8v af[AI], bfv[BJ];
#pragma unroll
            for (int i = 0; i < AI; i++)
                af[i] = *(const short8v*)&As[wm * WM + i * 16 + lr][g * 8];
#pragma unroll
            for (int j = 0; j < BJ; j++)
                bfv[j] = *(const short8v*)&Bs[wn * WN + j * 16 + lr][g * 8];
#pragma unroll
            for (int i = 0; i < AI; i++)
#pragma unroll
                for (int j = 0; j < BJ; j++)
                    acc[i][j] = mfma16(af[i], bfv[j], acc[i][j]);
        }
    }
#pragma unroll
    for (int i = 0; i < AI; i++) {
#pragma unroll
        for (int j = 0; j < BJ; j++) {
            int col = n0 + wn * WN + j * 16 + lr;
            float bv = BIAS ? bias[col] : 0.f;
#pragma unroll
            for (int r = 0; r < 4; r++) {
                int row = m0 + wm * WM + i * 16 + lg * 4 + r;
                float v = acc[i][j][r] * oscale + bv;
                if (ACT == 1) v = tanhf(v);
                if (ACT == 2) v = fmaxf(v, 0.f);
                size_t idx = (size_t)row * ldc + col;
                if (RES) v += res[idx];
                if (WF) outF[idx] = v;
                if (WB) outB[idx] = f2bf(v);
            }
        }
    }
}

// ---------------------------------------------------------------- gemm5: 128x128 dbuf, mfma32,
// COUNTED-vmcnt pipeline (T4): stage next tile, wait only the previous tile's 8
// loads (vmcnt(8)), raw barrier; compute; barrier. Prefetch stays in flight
// across barriers instead of the __syncthreads vmcnt(0) drain.
template<int ACT, bool BIAS, bool RES, bool WF, bool WB>
__global__ __launch_bounds__(256, 2) void gemm5(
    const short* __restrict__ A, int lda, long long a_zs,
    const short* __restrict__ Wt, int ldw, long long w_zs,
    const float* __restrict__ bias, long long bias_zs,
    const float* __restrict__ res, long long res_zs,
    float* __restrict__ outF, long long outF_zs,
    short* __restrict__ outB, long long outB_zs,
    int ldc, int K, float oscale) {
    constexpr int BM = 128, BN = 128, BK = 64;
    __shared__ short As[2][BM][BK];
    __shared__ short Bs[2][BN][BK];
    long long z = blockIdx.z;
    A += z * a_zs; Wt += z * w_zs;
    if (BIAS) bias += z * bias_zs;
    if (RES)  res  += z * res_zs;
    if (WF)   outF += z * outF_zs;
    if (WB)   outB += z * outB_zs;
    int m0 = blockIdx.x * BM, n0 = blockIdx.y * BN;
    int tid = threadIdx.x, wv = tid >> 6, l = tid & 63;
    int lq = l & 31, hi = l >> 5;
    int wm = wv & 1, wn = wv >> 1;
    f32x16 acc[2][2] = {};
    int lrow = l >> 3;
    int gcol = (l & 7) ^ lrow;

    auto STAGE = [&](int bi, int k0) {          // 8 global_load_lds per wave
#pragma unroll
        for (int c = 0; c < 4; c++) {
            int ch = wv + c * 4;
            gload_lds16(&A[(size_t)(m0 + ch * 8 + lrow) * lda + k0 + gcol * 8],
                        &As[bi][ch * 8][0]);
        }
#pragma unroll
        for (int c = 0; c < 4; c++) {
            int ch = wv + c * 4;
            gload_lds16(&Wt[(size_t)(n0 + ch * 8 + lrow) * ldw + k0 + gcol * 8],
                        &Bs[bi][ch * 8][0]);
        }
    };

    STAGE(0, 0);
    int NT = K / BK;
    for (int t = 0; t < NT; t++) {
        int cur = t & 1;
        if (t + 1 < NT) {
            STAGE(cur ^ 1, (t + 1) * BK);                    // +8 loads, stay in flight
            asm volatile("s_waitcnt vmcnt(8)" ::: "memory"); // prev tile's 8 landed
        } else {
            asm volatile("s_waitcnt vmcnt(0)" ::: "memory");
        }
        __builtin_amdgcn_sched_barrier(0);
        __builtin_amdgcn_s_barrier();           // buf[cur] ready for ALL waves
        const short (*Ac)[BK] = As[cur];
        const short (*Bc)[BK] = Bs[cur];
#pragma unroll
        for (int ks = 0; ks < 4; ks++) {
            int g = (ks * 2 + hi) ^ (lq & 7);
            short8v af[2], bf[2];
#pragma unroll
            for (int i = 0; i < 2; i++)
                af[i] = *(const short8v*)&Ac[wm * 64 + i * 32 + lq][g * 8];
#pragma unroll
            for (int j = 0; j < 2; j++)
                bf[j] = *(const short8v*)&Bc[wn * 64 + j * 32 + lq][g * 8];
#pragma unroll
            for (int i = 0; i < 2; i++)
#pragma unroll
                for (int j = 0; j < 2; j++)
                    acc[i][j] = mfma32(af[i], bf[j], acc[i][j]);
        }
        __builtin_amdgcn_sched_barrier(0);
        __builtin_amdgcn_s_barrier();           // all reads of buf[cur] done
    }
#pragma unroll
    for (int i = 0; i < 2; i++) {
#pragma unroll
        for (int j = 0; j < 2; j++) {
            int col = n0 + wn * 64 + j * 32 + lq;
            float bv = BIAS ? bias[col] : 0.f;
#pragma unroll
            for (int r = 0; r < 16; r++) {
                int row = m0 + wm * 64 + i * 32 + 4 * hi + (r & 3) + 8 * (r >> 2);
                float v = acc[i][j][r] * oscale + bv;
                if (ACT == 1) v = tanhf(v);
                if (ACT == 2) v = fmaxf(v, 0.f);
                size_t idx = (size_t)row * ldc + col;
                if (RES) v += res[idx];
                if (WF) outF[idx] = v;
                if (WB) outB[idx] = f2bf(v);
            }
        }
    }
}

// ---------------------------------------------------------------- gemm_kv: 128x128 tile = one head's K|V
__global__ __launch_bounds__(256, 2) void gemm_kv(
    const short* __restrict__ A, long long a_zs,
    const short* __restrict__ Wt, long long w_zs,
    short* __restrict__ outB, long long outB_zs,
    short* __restrict__ VTo, int K) {
    constexpr int BK = 64;
    __shared__ short As[128][BK];
    __shared__ short Bs[128][BK];
    __shared__ short Tv[64][136];
    long long z = blockIdx.z;
    A += z * a_zs; Wt += z * w_zs; outB += z * outB_zs;
    int m0 = blockIdx.x * 128, n0 = blockIdx.y * 128;
    int tid = threadIdx.x, wv = tid >> 6, l = tid & 63, lr = l & 15, lg = l >> 4;
    int wm = wv & 1, wn = wv >> 1;
    float4v acc[4][4] = {};
    int lrow = l >> 3;
    int gcol = (l & 7) ^ lrow;
    for (int k0 = 0; k0 < K; k0 += BK) {
        __syncthreads();
#pragma unroll
        for (int c = 0; c < 4; c++) {
            int ch = wv + c * 4;
            gload_lds16(&A[(size_t)(m0 + ch * 8 + lrow) * 512 + k0 + gcol * 8],
                        &As[ch * 8][0]);
        }
#pragma unroll
        for (int c = 0; c < 4; c++) {
            int ch = wv + c * 4;
            gload_lds16(&Wt[(size_t)(n0 + ch * 8 + lrow) * 512 + k0 + gcol * 8],
                        &Bs[ch * 8][0]);
        }
        __syncthreads();
#pragma unroll
        for (int kk = 0; kk < 2; kk++) {
            int g = (kk * 4 + lg) ^ (lr & 7);
            short8v af[4], bfv[4];
#pragma unroll
            for (int i = 0; i < 4; i++)
                af[i] = *(const short8v*)&As[wm * 64 + i * 16 + lr][g * 8];
#pragma unroll
            for (int j = 0; j < 4; j++)
                bfv[j] = *(const short8v*)&Bs[wn * 64 + j * 16 + lr][g * 8];
#pragma unroll
            for (int i = 0; i < 4; i++)
#pragma unroll
                for (int j = 0; j < 4; j++)
                    acc[i][j] = mfma16(af[i], bfv[j], acc[i][j]);
        }
    }
    if (wn == 0) {     // K-half: normal write, cols n0 + 0..63
#pragma unroll
        for (int i = 0; i < 4; i++)
#pragma unroll
            for (int j = 0; j < 4; j++) {
                int col = n0 + j * 16 + lr;
#pragma unroll
                for (int r = 0; r < 4; r++) {
                    int row = m0 + wm * 64 + i * 16 + lg * 4 + r;
                    outB[(size_t)row * 1024 + col] = f2bf(acc[i][j][r]);
                }
            }
    } else {           // V-half: stage transposed in LDS
#pragma unroll
        for (int i = 0; i < 4; i++)
#pragma unroll
            for (int j = 0; j < 4; j++) {
                int d = j * 16 + lr;
#pragma unroll
                for (int r = 0; r < 4; r++)
                    Tv[d][wm * 64 + i * 16 + lg * 4 + r] = f2bf(acc[i][j][r]);
            }
    }
    __syncthreads();
    int b = m0 >> 10, trow0 = m0 & 1023, h = n0 >> 7;
    short* dst = VTo + (size_t)(blockIdx.z * 64 + b * 8 + h) * 65536;
    int d = tid >> 2, c0 = (tid & 3) * 32;
#pragma unroll
    for (int q = 0; q < 4; q++)
        *(short8v*)&dst[(size_t)d * Tt + trow0 + c0 + q * 8] =
            *(const short8v*)&Tv[d][c0 + q * 8];
}

// ---------------------------------------------------------------- per-head proj2 (K=32)
__global__ __launch_bounds__(256) void proj2(const short* __restrict__ Z,
                                             const short* __restrict__ W2,
                                             short* __restrict__ Qo,
                                             short* __restrict__ Ko,
                                             short* __restrict__ VTo,
                                             float qscale) {
    __shared__ short As[64][40], Ws[64][40];
    __shared__ short Tv[64][72];
    int zz = blockIdx.y, t = zz >> 4, m = (zz >> 3) & 1, h = zz & 7;
    int m0 = blockIdx.x * 64;
    const short* Ap = Z + (size_t)m * ((size_t)ROWS * 768) + t * 256 + h * 32;
    const short* Wp = W2 + (size_t)zz * 2048;
    float sc = (t == 0) ? qscale : 1.0f;
    int tid = threadIdx.x, w = tid >> 6, l = tid & 63, lr = l & 15, lg = l >> 4;
    int r = tid >> 2, c = (tid & 3) * 8;
    *(short8v*)&As[r][c] = *(const short8v*)&Ap[(size_t)(m0 + r) * 768 + c];
    *(short8v*)&Ws[r][c] = *(const short8v*)&Wp[r * 32 + c];
    __syncthreads();
    short8v af = *(const short8v*)&As[w * 16 + lr][lg * 8];
    float4v acc[4] = {};
#pragma unroll
    for (int j = 0; j < 4; j++) {
        short8v bf = *(const short8v*)&Ws[j * 16 + lr][lg * 8];
        acc[j] = mfma16(af, bf, acc[j]);
    }
    if (t < 2) {
        short* Op = (t == 0 ? Qo : Ko) + (size_t)m * SLAB + h * 64;
#pragma unroll
        for (int j = 0; j < 4; j++)
#pragma unroll
            for (int rr = 0; rr < 4; rr++)
                Op[(size_t)(m0 + w * 16 + lg * 4 + rr) * 512 + j * 16 + lr] =
                    f2bf(acc[j][rr] * sc);
    } else {
#pragma unroll
        for (int j = 0; j < 4; j++)
#pragma unroll
            for (int rr = 0; rr < 4; rr++)
                Tv[j * 16 + lr][w * 16 + lg * 4 + rr] = f2bf(acc[j][rr]);
        __syncthreads();
        int b = m0 >> 10, trow0 = m0 & 1023;
        int z64 = m * 64 + b * 8 + h;
        short* dst = VTo + (size_t)z64 * 65536;
        int d = w * 16 + (l >> 2), toff = (l & 3) * 16;
        *(short8v*)&dst[(size_t)d * Tt + trow0 + toff]     = *(const short8v*)&Tv[d][toff];
        *(short8v*)&dst[(size_t)d * Tt + trow0 + toff + 8] = *(const short8v*)&Tv[d][toff + 8];
    }
}

// ---------------------------------------------------------------- flash attention v4
__global__ __launch_bounds__(512, 4) void flash_attn4(
    const short* __restrict__ Q, const short* __restrict__ K,
    const short* __restrict__ VT, short* __restrict__ O,
    int krs, int khs, long long qzs, long long kzs, long long vtzs, long long ozs)
{
    __shared__ short Ks[2][64][64];
    __shared__ short Vs[2][64][64];
    int id = blockIdx.x;
    int bh = id & 63, mod = (id >> 6) & 1, p = (id >> 7) & 3;
    Q += (long long)mod * qzs; K += (long long)mod * kzs;
    VT += (long long)mod * vtzs; O += (long long)mod * ozs;
    int b = bh >> 3, h = bh & 7;
    int tid = threadIdx.x, w = tid >> 6, l = tid & 63;
    int lq = l & 31, hi = l >> 5;
    int strip = (w < 4) ? p : 7 - p;
    int qwb = strip * 128 + (w & 3) * 32;
    int qabs = qwb + lq;
    const short* Qp = Q + (size_t)b * Tt * Cc + h * HSs;
    const short* Kp = K + (size_t)b * Tt * krs + h * khs;
    const short* Vp = VT + (size_t)bh * HSs * Tt;
    short* Op = O + (size_t)b * Tt * Cc + h * HSs;

    short8v qf[4];
#pragma unroll
    for (int c = 0; c < 4; c++)
        qf[c] = *(const short8v*)&Qp[(size_t)qabs * Cc + (c * 2 + hi) * 8];

    f32x16 oacc[2] = {};
    float mrun = -1e30f, lrun = 0.f;
    int nk = 2 * (7 - p) + 2;
    short8v pk, pv;

    auto LOADT = [&](int kb) {
        int r = tid >> 3, cg = (tid & 7) ^ (r & 7);
        pk = *(const short8v*)&Kp[(size_t)(kb + r) * krs + cg * 8];
        pv = *(const short8v*)&Vp[(size_t)r * Tt + kb + cg * 8];
    };
    auto STORET = [&](int bi) {
        int r = tid >> 3, cp = tid & 7;
        *(short8v*)&Ks[bi][r][cp * 8] = pk;
        *(short8v*)&Vs[bi][r][cp * 8] = pv;
    };

    LOADT(0); STORET(0); __syncthreads();

    for (int t = 0; t < nk; t++) {
        int cur = t & 1, kb = t * 64;
        bool pre = (t + 1 < nk);
        if (pre) LOADT(kb + 64);
        if (kb <= qwb + 31) {
            bool full = (kb + 63 <= qwb);
            f32x16 st[2] = {};
            __builtin_amdgcn_s_setprio(1);
#pragma unroll
            for (int kh = 0; kh < 2; kh++) {
#pragma unroll
                for (int cc = 0; cc < 4; cc++) {
                    int r = kh * 32 + lq;
                    int cp = (cc * 2 + hi) ^ (r & 7);
                    short8v af = *(const short8v*)&Ks[cur][r][cp * 8];
                    st[kh] = mfma32(af, qf[cc], st[kh]);
                }
            }
            __builtin_amdgcn_s_setprio(0);
            float pr[32];
            if (full) {
#pragma unroll
                for (int kh = 0; kh < 2; kh++)
#pragma unroll
                    for (int r = 0; r < 16; r++) pr[kh * 16 + r] = st[kh][r];
            } else {
#pragma unroll
                for (int kh = 0; kh < 2; kh++)
#pragma unroll
                    for (int r = 0; r < 16; r++) {
                        int kabs = kb + kh * 32 + (r & 3) + 8 * (r >> 2) + 4 * hi;
                        pr[kh * 16 + r] = (kabs <= qabs) ? st[kh][r] : -3.0e38f;
                    }
            }
            float t16[16];
#pragma unroll
            for (int i = 0; i < 16; i++) t16[i] = fmaxf(pr[i], pr[i + 16]);
#pragma unroll
            for (int i = 0; i < 8; i++) t16[i] = fmaxf(t16[i], t16[i + 8]);
            float mx = fmaxf(fmaxf(fmaxf(t16[0], t16[4]), fmaxf(t16[1], t16[5])),
                             fmaxf(fmaxf(t16[2], t16[6]), fmaxf(t16[3], t16[7])));
            mx = fmaxf(mx, __shfl_xor(mx, 32));
            if (!__all(mx <= mrun + 11.5f)) {
                float mn = fmaxf(mrun, mx);
                float al = EXP2F(mrun - mn);
                mrun = mn;
                lrun *= al;
#pragma unroll
                for (int dh = 0; dh < 2; dh++)
#pragma unroll
                    for (int r = 0; r < 16; r++) oacc[dh][r] *= al;
            }
#pragma unroll
            for (int i = 0; i < 32; i++) pr[i] = EXP2F(pr[i] - mrun);
            float s16[16];
#pragma unroll
            for (int i = 0; i < 16; i++) s16[i] = pr[i] + pr[i + 16];
#pragma unroll
            for (int i = 0; i < 8; i++) s16[i] = s16[i] + s16[i + 8];
            float rsum = ((s16[0] + s16[4]) + (s16[1] + s16[5])) +
                         ((s16[2] + s16[6]) + (s16[3] + s16[7]));
            rsum += __shfl_xor(rsum, 32);
            lrun += rsum;
#pragma unroll
            for (int ks = 0; ks < 4; ks++) {
                unsigned x0, x1, y0, y1;
                asm("v_cvt_pk_bf16_f32 %0, %1, %2" : "=v"(x0) : "v"(pr[ks*8+0]), "v"(pr[ks*8+1]));
                asm("v_cvt_pk_bf16_f32 %0, %1, %2" : "=v"(x1) : "v"(pr[ks*8+2]), "v"(pr[ks*8+3]));
                asm("v_cvt_pk_bf16_f32 %0, %1, %2" : "=v"(y0) : "v"(pr[ks*8+4]), "v"(pr[ks*8+5]));
                asm("v_cvt_pk_bf16_f32 %0, %1, %2" : "=v"(y1) : "v"(pr[ks*8+6]), "v"(pr[ks*8+7]));
                asm volatile("v_permlane32_swap_b32 %0, %1" : "+v"(x0), "+v"(y0));
                asm volatile("v_permlane32_swap_b32 %0, %1" : "+v"(x1), "+v"(y1));
                union { unsigned u[4]; short8v s; } uu;
                uu.u[0] = x0; uu.u[1] = x1; uu.u[2] = y0; uu.u[3] = y1;
                __builtin_amdgcn_s_setprio(1);
#pragma unroll
                for (int dh = 0; dh < 2; dh++) {
                    int r = dh * 32 + lq;
                    int cp = (ks * 2 + hi) ^ (r & 7);
                    short8v vf = *(const short8v*)&Vs[cur][r][cp * 8];
                    oacc[dh] = mfma32(vf, uu.s, oacc[dh]);
                }
                __builtin_amdgcn_s_setprio(0);
            }
        }
        if (pre) STORET(cur ^ 1);
        __syncthreads();
    }
    float inv = 1.f / lrun;
#pragma unroll
    for (int dh = 0; dh < 2; dh++)
#pragma unroll
        for (int r = 0; r < 16; r += 2) {
            unsigned wds;
            float a0 = oacc[dh][r] * inv, a1 = oacc[dh][r + 1] * inv;
            asm("v_cvt_pk_bf16_f32 %0, %1, %2" : "=v"(wds) : "v"(a0), "v"(a1));
            int d = (r & 3) + 8 * (r >> 2) + 4 * hi + dh * 32;
            *(unsigned*)&Op[(size_t)qabs * Cc + d] = wds;
        }
}

// ---------------------------------------------------------------- host
extern "C" void kernel_launch(void* const* d_in, const int* in_sizes, int n_in,
                              void* d_out, int out_size, void* d_ws, size_t ws_size,
                              hipStream_t stream) {
    (void)in_sizes; (void)n_in; (void)out_size; (void)ws_size;
    const float* X     = (const float*)d_in[0];
    const float* saKW1 = (const float*)d_in[1];
    const float* saKB1 = (const float*)d_in[2];
    const float* saKW2 = (const float*)d_in[3];
    const float* saQW1 = (const float*)d_in[4];
    const float* saQB1 = (const float*)d_in[5];
    const float* saQW2 = (const float*)d_in[6];
    const float* saVW1 = (const float*)d_in[7];
    const float* saVB1 = (const float*)d_in[8];
    const float* saVW2 = (const float*)d_in[9];
    const float* saPW1 = (const float*)d_in[10];
    const float* saPB1 = (const float*)d_in[11];
    const float* saPW2 = (const float*)d_in[12];
    const float* saPB2 = (const float*)d_in[13];
    const float* ffW1  = (const float*)d_in[14];
    const float* ffB1  = (const float*)d_in[15];
    const float* ffW2  = (const float*)d_in[16];
    const float* ffB2  = (const float*)d_in[17];
    const float* ln1g  = (const float*)d_in[18];
    const float* ln1b  = (const float*)d_in[19];
    const float* ln2g  = (const float*)d_in[20];
    const float* ln2b  = (const float*)d_in[21];
    const float* lncg  = (const float*)d_in[22];
    const float* lncb  = (const float*)d_in[23];
    const float* caQW  = (const float*)d_in[24];
    const float* caKVW = (const float*)d_in[25];
    const float* caPW1 = (const float*)d_in[26];
    const float* caPB1 = (const float*)d_in[27];
    const float* caPW2 = (const float*)d_in[28];
    const float* caPB2 = (const float*)d_in[29];
    float* OUT = (float*)d_out;

    char* ws = (char*)d_ws;
    size_t cur = 0;
    auto alloc = [&](size_t bytes) -> char* {
        char* p = ws + cur; cur += (bytes + 255) & ~(size_t)255; return p;
    };

    short* WT = (short*)alloc((size_t)7700480 * 2);
    size_t wo = 0;
    auto wslot = [&](size_t e) -> short* { short* p = WT + wo; wo += e; return p; };
    short* w_qkv1 = wslot(786432);
    short* w_qkv2 = wslot(98304);
    short* w_pw1 = wslot(262144); short* w_pw2 = wslot(262144);
    short* w_ff1 = wslot(2097152); short* w_ff2 = wslot(2097152);
    short* w_caq = wslot(524288);  short* w_cakv = wslot(1048576);
    short* w_cp1 = wslot(262144);  short* w_cp2 = wslot(262144);
    float* bqkv = (float*)alloc(2 * 768 * 4);

    short* Hb  = (short*)alloc(2 * SLAB * 2);
    short* Qb  = (short*)alloc(2 * SLAB * 2);
    short* Obf = (short*)alloc(2 * SLAB * 2);
    short* Fb  = (short*)alloc((size_t)2 * ROWS * 2048 * 2);
    short* AB  = (short*)alloc(2 * SLAB * 2);
    short* VTb = Hb;
    short* P1b = Hb;
    short* Kb = Fb + KOFF;

    // ---- one-launch weight transpose ----
    TPack tp;
    int base = 0, ti = 0;
    auto addT = [&](const float* s, short* d, int K, int N, int slices,
                    long long moff, long long hoff) {
        tp.d[ti++] = TDesc{s, d, K, N, moff, hoff, base};
        base += (K / 32) * (N / 32) * slices;
    };
    addT(saQW1, w_qkv1,          512, 32, 16, 393216, 16384);
    addT(saKW1, w_qkv1 + 131072, 512, 32, 16, 393216, 16384);
    addT(saVW1, w_qkv1 + 262144, 512, 32, 16, 393216, 16384);
    addT(saQW2, w_qkv2,          32, 64, 16, 16384, 2048);
    addT(saKW2, w_qkv2 + 32768,  32, 64, 16, 16384, 2048);
    addT(saVW2, w_qkv2 + 65536,  32, 64, 16, 16384, 2048);
    addT(saPW1, w_pw1, 512, 256, 2, 0, 131072);
    addT(saPW2, w_pw2, 256, 512, 2, 0, 131072);
    addT(ffW1,  w_ff1, 512, 2048, 2, 0, 1048576);
    addT(ffW2,  w_ff2, 2048, 512, 2, 0, 1048576);
    addT(caQW,  w_caq, 512, 64, 16, 262144, 32768);
    addT(caKVW, w_cakv, 512, 128, 16, 524288, 65536);
    addT(caPW1, w_cp1, 512, 256, 2, 0, 131072);
    addT(caPW2, w_cp2, 256, 512, 2, 0, 131072);
    transpose_all<<<dim3(base), 256, 0, stream>>>(tp);
    bias_cat3<<<2, 256, 0, stream>>>(saQB1, saKB1, saVB1, bqkv);

    // ---- self-attention + FF, both modalities batched via blockIdx.z ----
    ln_kernel<<<dim3(ROWS / 4, 2), 256, 0, stream>>>(X, ln1g, ln1b, Hb, BTC);
    gemm5<1, true, false, false, true><<<dim3(64, 6, 2), 256, 0, stream>>>(
        Hb, 512, SLAB, w_qkv1, 512, 393216, bqkv, 768,
        nullptr, 0, nullptr, 0, Fb, (long long)ROWS * 768, 768, 512, 1.0f);
    proj2<<<dim3(128, 48), 256, 0, stream>>>(Fb, w_qkv2, Qb, Kb, VTb, SCQ);
    flash_attn4<<<dim3(512), 512, 0, stream>>>(
        Qb, Kb, VTb, Obf, 512, 64, SLAB, SLAB, 4194304, SLAB);
    gemm2<64, 128, 1, true, false, false, true><<<dim3(128, 2, 2), 256, 0, stream>>>(
        Obf, 512, SLAB, w_pw1, 512, 131072, saPB1, 256,
        nullptr, 0, nullptr, 0, P1b, (long long)ROWS * 256, 256, 512, 1.0f);
    gemm2<64, 128, 0, true, true, true, true><<<dim3(128, 4, 2), 256, 0, stream>>>(
        P1b, 256, (long long)ROWS * 256, w_pw2, 256, 131072, saPB2, 512,
        X, BTC, OUT, BTC, Obf, SLAB, 512, 256, 1.0f);
    ln_bf<<<dim3(ROWS / 4, 2), 256, 0, stream>>>(Obf, ln2g, ln2b, Hb);
    gemm5<2, true, false, false, true><<<dim3(64, 16, 2), 256, 0, stream>>>(
        Hb, 512, SLAB, w_ff1, 512, 1048576, ffB1, 2048,
        nullptr, 0, nullptr, 0, Fb, (long long)ROWS * 2048, 2048, 512, 1.0f);
    gemm5<0, true, true, true, true><<<dim3(64, 4, 2), 256, 0, stream>>>(
        Fb, 2048, (long long)ROWS * 2048, w_ff2, 2048, 1048576, ffB2, 512,
        OUT, BTC, OUT, BTC, AB, SLAB, 512, 2048, 1.0f);

    // ---- cross-attention, both modalities batched ----
    ln_bf<<<dim3(ROWS / 4, 2), 256, 0, stream>>>(AB, lncg, lncb, Hb);
    gemm2<64, 128, 0, false, false, false, true><<<dim3(128, 4, 2), 256, 0, stream>>>(
        Hb, 512, SLAB, w_caq, 512, 262144, nullptr, 0,
        nullptr, 0, nullptr, 0, Qb, SLAB, 512, 512, SCQ);
    gemm_kv<<<dim3(64, 8, 2), 256, 0, stream>>>(
        AB + SLAB, -(long long)SLAB, w_cakv, 524288,
        Fb, (long long)ROWS * 1024, VTb, 512);
    flash_attn4<<<dim3(512), 512, 0, stream>>>(
        Qb, Fb, VTb, Obf, 1024, 128, SLAB, (long long)ROWS * 1024, 4194304, SLAB);
    gemm2<64, 128, 1, true, false, false, true><<<dim3(128, 2, 2), 256, 0, stream>>>(
        Obf, 512, SLAB, w_cp1, 512, 131072, caPB1, 256,
        nullptr, 0, nullptr, 0, P1b, (long long)ROWS * 256, 256, 512, 1.0f);
    gemm2<64, 128, 0, true, true, true, false><<<dim3(128, 4, 2), 256, 0, stream>>>(
        P1b, 256, (long long)ROWS * 256, w_cp2, 256, 131072, caPB2, 512,
        OUT, BTC, OUT, BTC, nullptr, 0, 512, 256, 1.0f);
}

// Round 13
// 345.631 us; speedup vs baseline: 1.0711x; 1.0711x over previous
//
#include <hip/hip_runtime.h>
#include <hip/hip_bf16.h>

#define DEVI __device__ __forceinline__

typedef __attribute__((ext_vector_type(8))) short short8v;   // 8 bf16
typedef __attribute__((ext_vector_type(4))) short short4v;   // 4 bf16
typedef __attribute__((ext_vector_type(4))) float float4v;
typedef __attribute__((ext_vector_type(16))) float f32x16;

#if defined(__has_builtin)
#if __has_builtin(__builtin_amdgcn_exp2f)
#define EXP2F(x) __builtin_amdgcn_exp2f(x)
#endif
#endif
#ifndef EXP2F
#define EXP2F(x) exp2f(x)
#endif

constexpr int Mm = 2, Bb = 8, Tt = 1024, Cc = 512, Hh = 8, HSs = 64;
constexpr int ROWS = Bb * Tt;                 // 8192 tokens per modality
constexpr size_t BTC = (size_t)Bb * Tt * Cc;  // f32 elems per modality tensor
constexpr size_t SLAB = (size_t)ROWS * 512;   // bf16 elems per modality slab
constexpr size_t KOFF = (size_t)2 * ROWS * 768;   // K region inside Fb
constexpr float SCQ = 0.18033688011112042f;       // 0.125 * log2(e)

DEVI short f2bf(float f) {
    __hip_bfloat16 h = __float2bfloat16(f);
    short s; __builtin_memcpy(&s, &h, 2); return s;
}
DEVI float bf2f(short s) {
    unsigned u = ((unsigned)(unsigned short)s) << 16;
    float f; __builtin_memcpy(&f, &u, 4); return f;
}

DEVI float4v mfma16(short8v a, short8v b, float4v c) {
    return __builtin_amdgcn_mfma_f32_16x16x32_bf16(a, b, c, 0, 0, 0);
}
DEVI f32x16 mfma32(short8v a, short8v b, f32x16 c) {
    return __builtin_amdgcn_mfma_f32_32x32x16_bf16(a, b, c, 0, 0, 0);
}

DEVI void gload_lds16(const short* g, short* l) {
    __builtin_amdgcn_global_load_lds(
        (const __attribute__((address_space(1))) void*)g,
        (__attribute__((address_space(3))) void*)l, 16, 0, 0);
}

// ---------------------------------------------------------------- mega transpose+convert
struct TDesc {
    const float* src; short* dst;
    int K, N;
    long long moff, hoff;
    int base;
};
struct TPack { TDesc d[14]; };

__global__ __launch_bounds__(256) void transpose_all(TPack p) {
    __shared__ float t[32][33];
    int bid = blockIdx.x;
    int di = 0;
#pragma unroll
    for (int i = 1; i < 14; i++) if (bid >= p.d[i].base) di = i;
    TDesc d = p.d[di];
    int local = bid - d.base;
    int kb = d.K >> 5, nb = d.N >> 5;
    int bx = local % kb; int rest = local / kb;
    int by = rest % nb;  int z = rest / nb;
    int k0 = bx * 32, n0 = by * 32;
    size_t so = (size_t)z * d.K * d.N;
    short* dst = d.dst + (size_t)(z >> 3) * d.moff + (size_t)(z & 7) * d.hoff;
    int tx = threadIdx.x & 31, ty = threadIdx.x >> 5;
#pragma unroll
    for (int i = 0; i < 32; i += 8)
        t[ty + i][tx] = d.src[so + (size_t)(k0 + ty + i) * d.N + n0 + tx];
    __syncthreads();
#pragma unroll
    for (int i = 0; i < 32; i += 8)
        dst[(size_t)(n0 + ty + i) * d.K + k0 + tx] = f2bf(t[tx][ty + i]);
}

// concat q/k/v biases (each (M,256) f32) -> (M, 768)
__global__ __launch_bounds__(256) void bias_cat3(const float* __restrict__ q,
                                                 const float* __restrict__ k,
                                                 const float* __restrict__ v,
                                                 float* __restrict__ o) {
    int m = blockIdx.x, t = threadIdx.x;
    o[m * 768 + t]       = q[m * 256 + t];
    o[m * 768 + 256 + t] = k[m * 256 + t];
    o[m * 768 + 512 + t] = v[m * 256 + t];
}

// ---------------------------------------------------------------- layernorm: f32 in, 1 wave/row
__global__ __launch_bounds__(256) void ln_kernel(const float* __restrict__ x,
                                                 const float* __restrict__ g,
                                                 const float* __restrict__ b,
                                                 short* __restrict__ out, size_t xzs) {
    int z = blockIdx.y;
    x += z * xzs; g += z * Cc; b += z * Cc; out += z * SLAB;
    int row = blockIdx.x * 4 + (threadIdx.x >> 6);
    int l = threadIdx.x & 63;
    const float* xr = x + (size_t)row * Cc;
    float4 a = *(const float4*)&xr[l * 4];
    float4 c = *(const float4*)&xr[256 + l * 4];
    float s = (a.x + a.y) + (a.z + a.w) + (c.x + c.y) + (c.z + c.w);
    float q = (a.x * a.x + a.y * a.y) + (a.z * a.z + a.w * a.w) +
              (c.x * c.x + c.y * c.y) + (c.z * c.z + c.w * c.w);
#pragma unroll
    for (int o = 1; o < 64; o <<= 1) { s += __shfl_xor(s, o, 64); q += __shfl_xor(q, o, 64); }
    float mu = s * (1.f / Cc);
    float var = q * (1.f / Cc) - mu * mu;
    float rs = rsqrtf(var + 1e-5f);
    float4 ga = *(const float4*)&g[l * 4],   gc = *(const float4*)&g[256 + l * 4];
    float4 ba = *(const float4*)&b[l * 4],   bc = *(const float4*)&b[256 + l * 4];
    short4v o1, o2;
    o1[0] = f2bf((a.x - mu) * rs * ga.x + ba.x);
    o1[1] = f2bf((a.y - mu) * rs * ga.y + ba.y);
    o1[2] = f2bf((a.z - mu) * rs * ga.z + ba.z);
    o1[3] = f2bf((a.w - mu) * rs * ga.w + ba.w);
    o2[0] = f2bf((c.x - mu) * rs * gc.x + bc.x);
    o2[1] = f2bf((c.y - mu) * rs * gc.y + bc.y);
    o2[2] = f2bf((c.z - mu) * rs * gc.z + bc.z);
    o2[3] = f2bf((c.w - mu) * rs * gc.w + bc.w);
    short* orow = out + (size_t)row * Cc;
    *(short4v*)&orow[l * 4]       = o1;
    *(short4v*)&orow[256 + l * 4] = o2;
}

// ---------------------------------------------------------------- layernorm: bf16 in, 1 wave/row
__global__ __launch_bounds__(256) void ln_bf(const short* __restrict__ x,
                                             const float* __restrict__ g,
                                             const float* __restrict__ b,
                                             short* __restrict__ out) {
    int z = blockIdx.y;
    x += z * SLAB; g += z * Cc; b += z * Cc; out += z * SLAB;
    int row = blockIdx.x * 4 + (threadIdx.x >> 6);
    int l = threadIdx.x & 63;
    const short* xr = x + (size_t)row * Cc;
    short8v v = *(const short8v*)&xr[l * 8];
    float xv[8];
    float s = 0.f, q = 0.f;
#pragma unroll
    for (int i = 0; i < 8; i++) {
        xv[i] = bf2f(v[i]);
        s += xv[i]; q += xv[i] * xv[i];
    }
#pragma unroll
    for (int o = 1; o < 64; o <<= 1) { s += __shfl_xor(s, o, 64); q += __shfl_xor(q, o, 64); }
    float mu = s * (1.f / Cc);
    float var = q * (1.f / Cc) - mu * mu;
    float rs = rsqrtf(var + 1e-5f);
    short8v ov;
#pragma unroll
    for (int i = 0; i < 8; i++) {
        float gg = g[l * 8 + i], bb = b[l * 8 + i];
        ov[i] = f2bf((xv[i] - mu) * rs * gg + bb);
    }
    *(short8v*)&out[(size_t)row * Cc + l * 8] = ov;
}

// ---------------------------------------------------------------- m97-style GEMM, z-batched
template<int BM, int BN, int ACT, bool BIAS, bool RES, bool WF, bool WB>
__global__ __launch_bounds__(256, 2) void gemm2(
    const short* __restrict__ A, int lda, long long a_zs,
    const short* __restrict__ Wt, int ldw, long long w_zs,
    const float* __restrict__ bias, long long bias_zs,
    const float* __restrict__ res, long long res_zs,
    float* __restrict__ outF, long long outF_zs,
    short* __restrict__ outB, long long outB_zs,
    int ldc, int K, float oscale) {
    constexpr int BK = 64;
    __shared__ short As[BM][BK];
    __shared__ short Bs[BN][BK];
    long long z = blockIdx.z;
    A += z * a_zs; Wt += z * w_zs;
    if (BIAS) bias += z * bias_zs;
    if (RES)  res  += z * res_zs;
    if (WF)   outF += z * outF_zs;
    if (WB)   outB += z * outB_zs;
    int m0 = blockIdx.x * BM, n0 = blockIdx.y * BN;
    int tid = threadIdx.x, wv = tid >> 6, l = tid & 63, lr = l & 15, lg = l >> 4;
    constexpr int WM = BM / 2, WN = BN / 2;
    int wm = wv & 1, wn = wv >> 1;
    constexpr int AI = WM / 16, BJ = WN / 16;
    float4v acc[AI][BJ] = {};
    int lrow = l >> 3;
    int gcol = (l & 7) ^ lrow;
    constexpr int CHA = BM / 8, CHB = BN / 8;
    for (int k0 = 0; k0 < K; k0 += BK) {
        __syncthreads();
#pragma unroll
        for (int c = 0; c < CHA / 4; c++) {
            int ch = wv + c * 4;
            gload_lds16(&A[(size_t)(m0 + ch * 8 + lrow) * lda + k0 + gcol * 8],
                        &As[ch * 8][0]);
        }
#pragma unroll
        for (int c = 0; c < CHB / 4; c++) {
            int ch = wv + c * 4;
            gload_lds16(&Wt[(size_t)(n0 + ch * 8 + lrow) * ldw + k0 + gcol * 8],
                        &Bs[ch * 8][0]);
        }
        __syncthreads();
#pragma unroll
        for (int kk = 0; kk < 2; kk++) {
            int g = (kk * 4 + lg) ^ (lr & 7);
            short8v af[AI], bfv[BJ];
#pragma unroll
            for (int i = 0; i < AI; i++)
                af[i] = *(const short8v*)&As[wm * WM + i * 16 + lr][g * 8];
#pragma unroll
            for (int j = 0; j < BJ; j++)
                bfv[j] = *(const short8v*)&Bs[wn * WN + j * 16 + lr][g * 8];
#pragma unroll
            for (int i = 0; i < AI; i++)
#pragma unroll
                for (int j = 0; j < BJ; j++)
                    acc[i][j] = mfma16(af[i], bfv[j], acc[i][j]);
        }
    }
#pragma unroll
    for (int i = 0; i < AI; i++) {
#pragma unroll
        for (int j = 0; j < BJ; j++) {
            int col = n0 + wn * WN + j * 16 + lr;
            float bv = BIAS ? bias[col] : 0.f;
#pragma unroll
            for (int r = 0; r < 4; r++) {
                int row = m0 + wm * WM + i * 16 + lg * 4 + r;
                float v = acc[i][j][r] * oscale + bv;
                if (ACT == 1) v = tanhf(v);
                if (ACT == 2) v = fmaxf(v, 0.f);
                size_t idx = (size_t)row * ldc + col;
                if (RES) v += res[idx];
                if (WF) outF[idx] = v;
                if (WB) outB[idx] = f2bf(v);
            }
        }
    }
}

// ---------------------------------------------------------------- gemm3: 128x128, dbuf, mfma32 (K=2048 only)
template<int ACT, bool BIAS, bool RES, bool WF, bool WB>
__global__ __launch_bounds__(256, 2) void gemm3(
    const short* __restrict__ A, int lda, long long a_zs,
    const short* __restrict__ Wt, int ldw, long long w_zs,
    const float* __restrict__ bias, long long bias_zs,
    const float* __restrict__ res, long long res_zs,
    float* __restrict__ outF, long long outF_zs,
    short* __restrict__ outB, long long outB_zs,
    int ldc, int K, float oscale) {
    constexpr int BM = 128, BN = 128, BK = 64;
    __shared__ short As[2][BM][BK];
    __shared__ short Bs[2][BN][BK];
    long long z = blockIdx.z;
    A += z * a_zs; Wt += z * w_zs;
    if (BIAS) bias += z * bias_zs;
    if (RES)  res  += z * res_zs;
    if (WF)   outF += z * outF_zs;
    if (WB)   outB += z * outB_zs;
    int m0 = blockIdx.x * BM, n0 = blockIdx.y * BN;
    int tid = threadIdx.x, wv = tid >> 6, l = tid & 63;
    int lq = l & 31, hi = l >> 5;
    int wm = wv & 1, wn = wv >> 1;
    f32x16 acc[2][2] = {};
    int lrow = l >> 3;
    int gcol = (l & 7) ^ lrow;

    auto STAGE = [&](int bi, int k0) {
#pragma unroll
        for (int c = 0; c < 4; c++) {
            int ch = wv + c * 4;
            gload_lds16(&A[(size_t)(m0 + ch * 8 + lrow) * lda + k0 + gcol * 8],
                        &As[bi][ch * 8][0]);
        }
#pragma unroll
        for (int c = 0; c < 4; c++) {
            int ch = wv + c * 4;
            gload_lds16(&Wt[(size_t)(n0 + ch * 8 + lrow) * ldw + k0 + gcol * 8],
                        &Bs[bi][ch * 8][0]);
        }
    };

    STAGE(0, 0);
    __syncthreads();
    int NT = K / BK;
    for (int t = 0; t < NT; t++) {
        int cur = t & 1;
        if (t + 1 < NT) STAGE(cur ^ 1, (t + 1) * BK);
        const short (*Ac)[BK] = As[cur];
        const short (*Bc)[BK] = Bs[cur];
#pragma unroll
        for (int ks = 0; ks < 4; ks++) {
            int g = (ks * 2 + hi) ^ (lq & 7);
            short8v af[2], bf[2];
#pragma unroll
            for (int i = 0; i < 2; i++)
                af[i] = *(const short8v*)&Ac[wm * 64 + i * 32 + lq][g * 8];
#pragma unroll
            for (int j = 0; j < 2; j++)
                bf[j] = *(const short8v*)&Bc[wn * 64 + j * 32 + lq][g * 8];
#pragma unroll
            for (int i = 0; i < 2; i++)
#pragma unroll
                for (int j = 0; j < 2; j++)
                    acc[i][j] = mfma32(af[i], bf[j], acc[i][j]);
        }
        __syncthreads();
    }
#pragma unroll
    for (int i = 0; i < 2; i++) {
#pragma unroll
        for (int j = 0; j < 2; j++) {
            int col = n0 + wn * 64 + j * 32 + lq;
            float bv = BIAS ? bias[col] : 0.f;
#pragma unroll
            for (int r = 0; r < 16; r++) {
                int row = m0 + wm * 64 + i * 32 + 4 * hi + (r & 3) + 8 * (r >> 2);
                float v = acc[i][j][r] * oscale + bv;
                if (ACT == 1) v = tanhf(v);
                if (ACT == 2) v = fmaxf(v, 0.f);
                size_t idx = (size_t)row * ldc + col;
                if (RES) v += res[idx];
                if (WF) outF[idx] = v;
                if (WB) outB[idx] = f2bf(v);
            }
        }
    }
}

// ---------------------------------------------------------------- gemm_kv: 128x128 tile = one head's K|V
__global__ __launch_bounds__(256, 2) void gemm_kv(
    const short* __restrict__ A, long long a_zs,
    const short* __restrict__ Wt, long long w_zs,
    short* __restrict__ outB, long long outB_zs,
    short* __restrict__ VTo, int K) {
    constexpr int BK = 64;
    __shared__ short As[128][BK];
    __shared__ short Bs[128][BK];
    __shared__ short Tv[64][136];
    long long z = blockIdx.z;
    A += z * a_zs; Wt += z * w_zs; outB += z * outB_zs;
    int m0 = blockIdx.x * 128, n0 = blockIdx.y * 128;
    int tid = threadIdx.x, wv = tid >> 6, l = tid & 63, lr = l & 15, lg = l >> 4;
    int wm = wv & 1, wn = wv >> 1;
    float4v acc[4][4] = {};
    int lrow = l >> 3;
    int gcol = (l & 7) ^ lrow;
    for (int k0 = 0; k0 < K; k0 += BK) {
        __syncthreads();
#pragma unroll
        for (int c = 0; c < 4; c++) {
            int ch = wv + c * 4;
            gload_lds16(&A[(size_t)(m0 + ch * 8 + lrow) * 512 + k0 + gcol * 8],
                        &As[ch * 8][0]);
        }
#pragma unroll
        for (int c = 0; c < 4; c++) {
            int ch = wv + c * 4;
            gload_lds16(&Wt[(size_t)(n0 + ch * 8 + lrow) * 512 + k0 + gcol * 8],
                        &Bs[ch * 8][0]);
        }
        __syncthreads();
#pragma unroll
        for (int kk = 0; kk < 2; kk++) {
            int g = (kk * 4 + lg) ^ (lr & 7);
            short8v af[4], bfv[4];
#pragma unroll
            for (int i = 0; i < 4; i++)
                af[i] = *(const short8v*)&As[wm * 64 + i * 16 + lr][g * 8];
#pragma unroll
            for (int j = 0; j < 4; j++)
                bfv[j] = *(const short8v*)&Bs[wn * 64 + j * 16 + lr][g * 8];
#pragma unroll
            for (int i = 0; i < 4; i++)
#pragma unroll
                for (int j = 0; j < 4; j++)
                    acc[i][j] = mfma16(af[i], bfv[j], acc[i][j]);
        }
    }
    if (wn == 0) {     // K-half: normal write, cols n0 + 0..63
#pragma unroll
        for (int i = 0; i < 4; i++)
#pragma unroll
            for (int j = 0; j < 4; j++) {
                int col = n0 + j * 16 + lr;
#pragma unroll
                for (int r = 0; r < 4; r++) {
                    int row = m0 + wm * 64 + i * 16 + lg * 4 + r;
                    outB[(size_t)row * 1024 + col] = f2bf(acc[i][j][r]);
                }
            }
    } else {           // V-half: stage transposed in LDS
#pragma unroll
        for (int i = 0; i < 4; i++)
#pragma unroll
            for (int j = 0; j < 4; j++) {
                int d = j * 16 + lr;
#pragma unroll
                for (int r = 0; r < 4; r++)
                    Tv[d][wm * 64 + i * 16 + lg * 4 + r] = f2bf(acc[i][j][r]);
            }
    }
    __syncthreads();
    int b = m0 >> 10, trow0 = m0 & 1023, h = n0 >> 7;
    short* dst = VTo + (size_t)(blockIdx.z * 64 + b * 8 + h) * 65536;
    int d = tid >> 2, c0 = (tid & 3) * 32;
#pragma unroll
    for (int q = 0; q < 4; q++)
        *(short8v*)&dst[(size_t)d * Tt + trow0 + c0 + q * 8] =
            *(const short8v*)&Tv[d][c0 + q * 8];
}

// ---------------------------------------------------------------- per-head proj2 (K=32)
__global__ __launch_bounds__(256) void proj2(const short* __restrict__ Z,
                                             const short* __restrict__ W2,
                                             short* __restrict__ Qo,
                                             short* __restrict__ Ko,
                                             short* __restrict__ VTo,
                                             float qscale) {
    __shared__ short As[64][40], Ws[64][40];
    __shared__ short Tv[64][72];
    int zz = blockIdx.y, t = zz >> 4, m = (zz >> 3) & 1, h = zz & 7;
    int m0 = blockIdx.x * 64;
    const short* Ap = Z + (size_t)m * ((size_t)ROWS * 768) + t * 256 + h * 32;
    const short* Wp = W2 + (size_t)zz * 2048;
    float sc = (t == 0) ? qscale : 1.0f;
    int tid = threadIdx.x, w = tid >> 6, l = tid & 63, lr = l & 15, lg = l >> 4;
    int r = tid >> 2, c = (tid & 3) * 8;
    *(short8v*)&As[r][c] = *(const short8v*)&Ap[(size_t)(m0 + r) * 768 + c];
    *(short8v*)&Ws[r][c] = *(const short8v*)&Wp[r * 32 + c];
    __syncthreads();
    short8v af = *(const short8v*)&As[w * 16 + lr][lg * 8];
    float4v acc[4] = {};
#pragma unroll
    for (int j = 0; j < 4; j++) {
        short8v bf = *(const short8v*)&Ws[j * 16 + lr][lg * 8];
        acc[j] = mfma16(af, bf, acc[j]);
    }
    if (t < 2) {
        short* Op = (t == 0 ? Qo : Ko) + (size_t)m * SLAB + h * 64;
#pragma unroll
        for (int j = 0; j < 4; j++)
#pragma unroll
            for (int rr = 0; rr < 4; rr++)
                Op[(size_t)(m0 + w * 16 + lg * 4 + rr) * 512 + j * 16 + lr] =
                    f2bf(acc[j][rr] * sc);
    } else {
#pragma unroll
        for (int j = 0; j < 4; j++)
#pragma unroll
            for (int rr = 0; rr < 4; rr++)
                Tv[j * 16 + lr][w * 16 + lg * 4 + rr] = f2bf(acc[j][rr]);
        __syncthreads();
        int b = m0 >> 10, trow0 = m0 & 1023;
        int z64 = m * 64 + b * 8 + h;
        short* dst = VTo + (size_t)z64 * 65536;
        int d = w * 16 + (l >> 2), toff = (l & 3) * 16;
        *(short8v*)&dst[(size_t)d * Tt + trow0 + toff]     = *(const short8v*)&Tv[d][toff];
        *(short8v*)&dst[(size_t)d * Tt + trow0 + toff + 8] = *(const short8v*)&Tv[d][toff + 8];
    }
}

// ---------------------------------------------------------------- flash attention v4
__global__ __launch_bounds__(512, 4) void flash_attn4(
    const short* __restrict__ Q, const short* __restrict__ K,
    const short* __restrict__ VT, short* __restrict__ O,
    int krs, int khs, long long qzs, long long kzs, long long vtzs, long long ozs)
{
    __shared__ short Ks[2][64][64];
    __shared__ short Vs[2][64][64];
    int id = blockIdx.x;
    int bh = id & 63, mod = (id >> 6) & 1, p = (id >> 7) & 3;
    Q += (long long)mod * qzs; K += (long long)mod * kzs;
    VT += (long long)mod * vtzs; O += (long long)mod * ozs;
    int b = bh >> 3, h = bh & 7;
    int tid = threadIdx.x, w = tid >> 6, l = tid & 63;
    int lq = l & 31, hi = l >> 5;
    int strip = (w < 4) ? p : 7 - p;
    int qwb = strip * 128 + (w & 3) * 32;
    int qabs = qwb + lq;
    const short* Qp = Q + (size_t)b * Tt * Cc + h * HSs;
    const short* Kp = K + (size_t)b * Tt * krs + h * khs;
    const short* Vp = VT + (size_t)bh * HSs * Tt;
    short* Op = O + (size_t)b * Tt * Cc + h * HSs;

    short8v qf[4];
#pragma unroll
    for (int c = 0; c < 4; c++)
        qf[c] = *(const short8v*)&Qp[(size_t)qabs * Cc + (c * 2 + hi) * 8];

    f32x16 oacc[2] = {};
    float mrun = -1e30f, lrun = 0.f;
    int nk = 2 * (7 - p) + 2;
    short8v pk, pv;

    auto LOADT = [&](int kb) {
        int r = tid >> 3, cg = (tid & 7) ^ (r & 7);
        pk = *(const short8v*)&Kp[(size_t)(kb + r) * krs + cg * 8];
        pv = *(const short8v*)&Vp[(size_t)r * Tt + kb + cg * 8];
    };
    auto STORET = [&](int bi) {
        int r = tid >> 3, cp = tid & 7;
        *(short8v*)&Ks[bi][r][cp * 8] = pk;
        *(short8v*)&Vs[bi][r][cp * 8] = pv;
    };

    LOADT(0); STORET(0); __syncthreads();

    for (int t = 0; t < nk; t++) {
        int cur = t & 1, kb = t * 64;
        bool pre = (t + 1 < nk);
        if (pre) LOADT(kb + 64);
        if (kb <= qwb + 31) {
            bool full = (kb + 63 <= qwb);
            f32x16 st[2] = {};
            __builtin_amdgcn_s_setprio(1);
#pragma unroll
            for (int kh = 0; kh < 2; kh++) {
#pragma unroll
                for (int cc = 0; cc < 4; cc++) {
                    int r = kh * 32 + lq;
                    int cp = (cc * 2 + hi) ^ (r & 7);
                    short8v af = *(const short8v*)&Ks[cur][r][cp * 8];
                    st[kh] = mfma32(af, qf[cc], st[kh]);
                }
            }
            __builtin_amdgcn_s_setprio(0);
            float pr[32];
            if (full) {
#pragma unroll
                for (int kh = 0; kh < 2; kh++)
#pragma unroll
                    for (int r = 0; r < 16; r++) pr[kh * 16 + r] = st[kh][r];
            } else {
#pragma unroll
                for (int kh = 0; kh < 2; kh++)
#pragma unroll
                    for (int r = 0; r < 16; r++) {
                        int kabs = kb + kh * 32 + (r & 3) + 8 * (r >> 2) + 4 * hi;
                        pr[kh * 16 + r] = (kabs <= qabs) ? st[kh][r] : -3.0e38f;
                    }
            }
            float t16[16];
#pragma unroll
            for (int i = 0; i < 16; i++) t16[i] = fmaxf(pr[i], pr[i + 16]);
#pragma unroll
            for (int i = 0; i < 8; i++) t16[i] = fmaxf(t16[i], t16[i + 8]);
            float mx = fmaxf(fmaxf(fmaxf(t16[0], t16[4]), fmaxf(t16[1], t16[5])),
                             fmaxf(fmaxf(t16[2], t16[6]), fmaxf(t16[3], t16[7])));
            mx = fmaxf(mx, __shfl_xor(mx, 32));
            if (!__all(mx <= mrun + 11.5f)) {
                float mn = fmaxf(mrun, mx);
                float al = EXP2F(mrun - mn);
                mrun = mn;
                lrun *= al;
#pragma unroll
                for (int dh = 0; dh < 2; dh++)
#pragma unroll
                    for (int r = 0; r < 16; r++) oacc[dh][r] *= al;
            }
#pragma unroll
            for (int i = 0; i < 32; i++) pr[i] = EXP2F(pr[i] - mrun);
            float s16[16];
#pragma unroll
            for (int i = 0; i < 16; i++) s16[i] = pr[i] + pr[i + 16];
#pragma unroll
            for (int i = 0; i < 8; i++) s16[i] = s16[i] + s16[i + 8];
            float rsum = ((s16[0] + s16[4]) + (s16[1] + s16[5])) +
                         ((s16[2] + s16[6]) + (s16[3] + s16[7]));
            rsum += __shfl_xor(rsum, 32);
            lrun += rsum;
#pragma unroll
            for (int ks = 0; ks < 4; ks++) {
                unsigned x0, x1, y0, y1;
                asm("v_cvt_pk_bf16_f32 %0, %1, %2" : "=v"(x0) : "v"(pr[ks*8+0]), "v"(pr[ks*8+1]));
                asm("v_cvt_pk_bf16_f32 %0, %1, %2" : "=v"(x1) : "v"(pr[ks*8+2]), "v"(pr[ks*8+3]));
                asm("v_cvt_pk_bf16_f32 %0, %1, %2" : "=v"(y0) : "v"(pr[ks*8+4]), "v"(pr[ks*8+5]));
                asm("v_cvt_pk_bf16_f32 %0, %1, %2" : "=v"(y1) : "v"(pr[ks*8+6]), "v"(pr[ks*8+7]));
                asm volatile("v_permlane32_swap_b32 %0, %1" : "+v"(x0), "+v"(y0));
                asm volatile("v_permlane32_swap_b32 %0, %1" : "+v"(x1), "+v"(y1));
                union { unsigned u[4]; short8v s; } uu;
                uu.u[0] = x0; uu.u[1] = x1; uu.u[2] = y0; uu.u[3] = y1;
                __builtin_amdgcn_s_setprio(1);
#pragma unroll
                for (int dh = 0; dh < 2; dh++) {
                    int r = dh * 32 + lq;
                    int cp = (ks * 2 + hi) ^ (r & 7);
                    short8v vf = *(const short8v*)&Vs[cur][r][cp * 8];
                    oacc[dh] = mfma32(vf, uu.s, oacc[dh]);
                }
                __builtin_amdgcn_s_setprio(0);
            }
        }
        if (pre) STORET(cur ^ 1);
        __syncthreads();
    }
    float inv = 1.f / lrun;
#pragma unroll
    for (int dh = 0; dh < 2; dh++)
#pragma unroll
        for (int r = 0; r < 16; r += 2) {
            unsigned wds;
            float a0 = oacc[dh][r] * inv, a1 = oacc[dh][r + 1] * inv;
            asm("v_cvt_pk_bf16_f32 %0, %1, %2" : "=v"(wds) : "v"(a0), "v"(a1));
            int d = (r & 3) + 8 * (r >> 2) + 4 * hi + dh * 32;
            *(unsigned*)&Op[(size_t)qabs * Cc + d] = wds;
        }
}

// ---------------------------------------------------------------- host
extern "C" void kernel_launch(void* const* d_in, const int* in_sizes, int n_in,
                              void* d_out, int out_size, void* d_ws, size_t ws_size,
                              hipStream_t stream) {
    (void)in_sizes; (void)n_in; (void)out_size; (void)ws_size;
    const float* X     = (const float*)d_in[0];
    const float* saKW1 = (const float*)d_in[1];
    const float* saKB1 = (const float*)d_in[2];
    const float* saKW2 = (const float*)d_in[3];
    const float* saQW1 = (const float*)d_in[4];
    const float* saQB1 = (const float*)d_in[5];
    const float* saQW2 = (const float*)d_in[6];
    const float* saVW1 = (const float*)d_in[7];
    const float* saVB1 = (const float*)d_in[8];
    const float* saVW2 = (const float*)d_in[9];
    const float* saPW1 = (const float*)d_in[10];
    const float* saPB1 = (const float*)d_in[11];
    const float* saPW2 = (const float*)d_in[12];
    const float* saPB2 = (const float*)d_in[13];
    const float* ffW1  = (const float*)d_in[14];
    const float* ffB1  = (const float*)d_in[15];
    const float* ffW2  = (const float*)d_in[16];
    const float* ffB2  = (const float*)d_in[17];
    const float* ln1g  = (const float*)d_in[18];
    const float* ln1b  = (const float*)d_in[19];
    const float* ln2g  = (const float*)d_in[20];
    const float* ln2b  = (const float*)d_in[21];
    const float* lncg  = (const float*)d_in[22];
    const float* lncb  = (const float*)d_in[23];
    const float* caQW  = (const float*)d_in[24];
    const float* caKVW = (const float*)d_in[25];
    const float* caPW1 = (const float*)d_in[26];
    const float* caPB1 = (const float*)d_in[27];
    const float* caPW2 = (const float*)d_in[28];
    const float* caPB2 = (const float*)d_in[29];
    float* OUT = (float*)d_out;

    char* ws = (char*)d_ws;
    size_t cur = 0;
    auto alloc = [&](size_t bytes) -> char* {
        char* p = ws + cur; cur += (bytes + 255) & ~(size_t)255; return p;
    };

    short* WT = (short*)alloc((size_t)7700480 * 2);
    size_t wo = 0;
    auto wslot = [&](size_t e) -> short* { short* p = WT + wo; wo += e; return p; };
    short* w_qkv1 = wslot(786432);
    short* w_qkv2 = wslot(98304);
    short* w_pw1 = wslot(262144); short* w_pw2 = wslot(262144);
    short* w_ff1 = wslot(2097152); short* w_ff2 = wslot(2097152);
    short* w_caq = wslot(524288);  short* w_cakv = wslot(1048576);
    short* w_cp1 = wslot(262144);  short* w_cp2 = wslot(262144);
    float* bqkv = (float*)alloc(2 * 768 * 4);

    short* Hb  = (short*)alloc(2 * SLAB * 2);
    short* Qb  = (short*)alloc(2 * SLAB * 2);
    short* Obf = (short*)alloc(2 * SLAB * 2);
    short* Fb  = (short*)alloc((size_t)2 * ROWS * 2048 * 2);
    short* AB  = (short*)alloc(2 * SLAB * 2);
    short* VTb = Hb;
    short* P1b = Hb;
    short* Kb = Fb + KOFF;

    // ---- one-launch weight transpose ----
    TPack tp;
    int base = 0, ti = 0;
    auto addT = [&](const float* s, short* d, int K, int N, int slices,
                    long long moff, long long hoff) {
        tp.d[ti++] = TDesc{s, d, K, N, moff, hoff, base};
        base += (K / 32) * (N / 32) * slices;
    };
    addT(saQW1, w_qkv1,          512, 32, 16, 393216, 16384);
    addT(saKW1, w_qkv1 + 131072, 512, 32, 16, 393216, 16384);
    addT(saVW1, w_qkv1 + 262144, 512, 32, 16, 393216, 16384);
    addT(saQW2, w_qkv2,          32, 64, 16, 16384, 2048);
    addT(saKW2, w_qkv2 + 32768,  32, 64, 16, 16384, 2048);
    addT(saVW2, w_qkv2 + 65536,  32, 64, 16, 16384, 2048);
    addT(saPW1, w_pw1, 512, 256, 2, 0, 131072);
    addT(saPW2, w_pw2, 256, 512, 2, 0, 131072);
    addT(ffW1,  w_ff1, 512, 2048, 2, 0, 1048576);
    addT(ffW2,  w_ff2, 2048, 512, 2, 0, 1048576);
    addT(caQW,  w_caq, 512, 64, 16, 262144, 32768);
    addT(caKVW, w_cakv, 512, 128, 16, 524288, 65536);
    addT(caPW1, w_cp1, 512, 256, 2, 0, 131072);
    addT(caPW2, w_cp2, 256, 512, 2, 0, 131072);
    transpose_all<<<dim3(base), 256, 0, stream>>>(tp);
    bias_cat3<<<2, 256, 0, stream>>>(saQB1, saKB1, saVB1, bqkv);

    // ---- self-attention + FF, both modalities batched via blockIdx.z ----
    ln_kernel<<<dim3(ROWS / 4, 2), 256, 0, stream>>>(X, ln1g, ln1b, Hb, BTC);
    gemm2<128, 128, 1, true, false, false, true><<<dim3(64, 6, 2), 256, 0, stream>>>(
        Hb, 512, SLAB, w_qkv1, 512, 393216, bqkv, 768,
        nullptr, 0, nullptr, 0, Fb, (long long)ROWS * 768, 768, 512, 1.0f);
    proj2<<<dim3(128, 48), 256, 0, stream>>>(Fb, w_qkv2, Qb, Kb, VTb, SCQ);
    flash_attn4<<<dim3(512), 512, 0, stream>>>(
        Qb, Kb, VTb, Obf, 512, 64, SLAB, SLAB, 4194304, SLAB);
    gemm2<64, 128, 1, true, false, false, true><<<dim3(128, 2, 2), 256, 0, stream>>>(
        Obf, 512, SLAB, w_pw1, 512, 131072, saPB1, 256,
        nullptr, 0, nullptr, 0, P1b, (long long)ROWS * 256, 256, 512, 1.0f);
    gemm2<64, 128, 0, true, true, true, true><<<dim3(128, 4, 2), 256, 0, stream>>>(
        P1b, 256, (long long)ROWS * 256, w_pw2, 256, 131072, saPB2, 512,
        X, BTC, OUT, BTC, Obf, SLAB, 512, 256, 1.0f);
    ln_bf<<<dim3(ROWS / 4, 2), 256, 0, stream>>>(Obf, ln2g, ln2b, Hb);
    gemm2<128, 128, 2, true, false, false, true><<<dim3(64, 16, 2), 256, 0, stream>>>(
        Hb, 512, SLAB, w_ff1, 512, 1048576, ffB1, 2048,
        nullptr, 0, nullptr, 0, Fb, (long long)ROWS * 2048, 2048, 512, 1.0f);
    gemm3<0, true, true, true, true><<<dim3(64, 4, 2), 256, 0, stream>>>(
        Fb, 2048, (long long)ROWS * 2048, w_ff2, 2048, 1048576, ffB2, 512,
        OUT, BTC, OUT, BTC, AB, SLAB, 512, 2048, 1.0f);

    // ---- cross-attention, both modalities batched ----
    ln_bf<<<dim3(ROWS / 4, 2), 256, 0, stream>>>(AB, lncg, lncb, Hb);
    gemm2<64, 128, 0, false, false, false, true><<<dim3(128, 4, 2), 256, 0, stream>>>(
        Hb, 512, SLAB, w_caq, 512, 262144, nullptr, 0,
        nullptr, 0, nullptr, 0, Qb, SLAB, 512, 512, SCQ);
    gemm_kv<<<dim3(64, 8, 2), 256, 0, stream>>>(
        AB + SLAB, -(long long)SLAB, w_cakv, 524288,
        Fb, (long long)ROWS * 1024, VTb, 512);
    flash_attn4<<<dim3(512), 512, 0, stream>>>(
        Qb, Fb, VTb, Obf, 1024, 128, SLAB, (long long)ROWS * 1024, 4194304, SLAB);
    gemm2<64, 128, 1, true, false, false, true><<<dim3(128, 2, 2), 256, 0, stream>>>(
        Obf, 512, SLAB, w_cp1, 512, 131072, caPB1, 256,
        nullptr, 0, nullptr, 0, P1b, (long long)ROWS * 256, 256, 512, 1.0f);
    gemm2<64, 128, 0, true, true, true, false><<<dim3(128, 4, 2), 256, 0, stream>>>(
        P1b, 256, (long long)ROWS * 256, w_cp2, 256, 131072, caPB2, 512,
        OUT, BTC, OUT, BTC, nullptr, 0, 512, 256, 1.0f);
}

// Round 14
// 330.234 us; speedup vs baseline: 1.1210x; 1.0466x over previous
//
#include <hip/hip_runtime.h>
#include <hip/hip_bf16.h>

#define DEVI __device__ __forceinline__

typedef __attribute__((ext_vector_type(8))) short short8v;   // 8 bf16
typedef __attribute__((ext_vector_type(4))) short short4v;   // 4 bf16
typedef __attribute__((ext_vector_type(4))) float float4v;
typedef __attribute__((ext_vector_type(16))) float f32x16;

#if defined(__has_builtin)
#if __has_builtin(__builtin_amdgcn_exp2f)
#define EXP2F(x) __builtin_amdgcn_exp2f(x)
#endif
#endif
#ifndef EXP2F
#define EXP2F(x) exp2f(x)
#endif

constexpr int Mm = 2, Bb = 8, Tt = 1024, Cc = 512, Hh = 8, HSs = 64;
constexpr int ROWS = Bb * Tt;                 // 8192 tokens per modality
constexpr size_t BTC = (size_t)Bb * Tt * Cc;  // f32 elems per modality tensor
constexpr size_t SLAB = (size_t)ROWS * 512;   // bf16 elems per modality slab
constexpr size_t KOFF = (size_t)2 * ROWS * 768;   // K region inside Fb
constexpr float SCQ = 0.18033688011112042f;       // 0.125 * log2(e)

DEVI short f2bf(float f) {
    __hip_bfloat16 h = __float2bfloat16(f);
    short s; __builtin_memcpy(&s, &h, 2); return s;
}
DEVI float bf2f(short s) {
    unsigned u = ((unsigned)(unsigned short)s) << 16;
    float f; __builtin_memcpy(&f, &u, 4); return f;
}

DEVI float4v mfma16(short8v a, short8v b, float4v c) {
    return __builtin_amdgcn_mfma_f32_16x16x32_bf16(a, b, c, 0, 0, 0);
}
DEVI f32x16 mfma32(short8v a, short8v b, f32x16 c) {
    return __builtin_amdgcn_mfma_f32_32x32x16_bf16(a, b, c, 0, 0, 0);
}

DEVI void gload_lds16(const short* g, short* l) {
    __builtin_amdgcn_global_load_lds(
        (const __attribute__((address_space(1))) void*)g,
        (__attribute__((address_space(3))) void*)l, 16, 0, 0);
}

// ---------------------------------------------------------------- mega transpose+convert
struct TDesc {
    const float* src; short* dst;
    int K, N;
    long long moff, hoff;
    int base;
};
struct TPack { TDesc d[14]; };

__global__ __launch_bounds__(256) void transpose_all(TPack p) {
    __shared__ float t[32][33];
    int bid = blockIdx.x;
    int di = 0;
#pragma unroll
    for (int i = 1; i < 14; i++) if (bid >= p.d[i].base) di = i;
    TDesc d = p.d[di];
    int local = bid - d.base;
    int kb = d.K >> 5, nb = d.N >> 5;
    int bx = local % kb; int rest = local / kb;
    int by = rest % nb;  int z = rest / nb;
    int k0 = bx * 32, n0 = by * 32;
    size_t so = (size_t)z * d.K * d.N;
    short* dst = d.dst + (size_t)(z >> 3) * d.moff + (size_t)(z & 7) * d.hoff;
    int tx = threadIdx.x & 31, ty = threadIdx.x >> 5;
#pragma unroll
    for (int i = 0; i < 32; i += 8)
        t[ty + i][tx] = d.src[so + (size_t)(k0 + ty + i) * d.N + n0 + tx];
    __syncthreads();
#pragma unroll
    for (int i = 0; i < 32; i += 8)
        dst[(size_t)(n0 + ty + i) * d.K + k0 + tx] = f2bf(t[tx][ty + i]);
}

// concat q/k/v biases (each (M,256) f32) -> (M, 768)
__global__ __launch_bounds__(256) void bias_cat3(const float* __restrict__ q,
                                                 const float* __restrict__ k,
                                                 const float* __restrict__ v,
                                                 float* __restrict__ o) {
    int m = blockIdx.x, t = threadIdx.x;
    o[m * 768 + t]       = q[m * 256 + t];
    o[m * 768 + 256 + t] = k[m * 256 + t];
    o[m * 768 + 512 + t] = v[m * 256 + t];
}

// ---------------------------------------------------------------- layernorm: f32 in, 1 wave/row
__global__ __launch_bounds__(256) void ln_kernel(const float* __restrict__ x,
                                                 const float* __restrict__ g,
                                                 const float* __restrict__ b,
                                                 short* __restrict__ out, size_t xzs) {
    int z = blockIdx.y;
    x += z * xzs; g += z * Cc; b += z * Cc; out += z * SLAB;
    int row = blockIdx.x * 4 + (threadIdx.x >> 6);
    int l = threadIdx.x & 63;
    const float* xr = x + (size_t)row * Cc;
    float4 a = *(const float4*)&xr[l * 4];
    float4 c = *(const float4*)&xr[256 + l * 4];
    float s = (a.x + a.y) + (a.z + a.w) + (c.x + c.y) + (c.z + c.w);
    float q = (a.x * a.x + a.y * a.y) + (a.z * a.z + a.w * a.w) +
              (c.x * c.x + c.y * c.y) + (c.z * c.z + c.w * c.w);
#pragma unroll
    for (int o = 1; o < 64; o <<= 1) { s += __shfl_xor(s, o, 64); q += __shfl_xor(q, o, 64); }
    float mu = s * (1.f / Cc);
    float var = q * (1.f / Cc) - mu * mu;
    float rs = rsqrtf(var + 1e-5f);
    float4 ga = *(const float4*)&g[l * 4],   gc = *(const float4*)&g[256 + l * 4];
    float4 ba = *(const float4*)&b[l * 4],   bc = *(const float4*)&b[256 + l * 4];
    short4v o1, o2;
    o1[0] = f2bf((a.x - mu) * rs * ga.x + ba.x);
    o1[1] = f2bf((a.y - mu) * rs * ga.y + ba.y);
    o1[2] = f2bf((a.z - mu) * rs * ga.z + ba.z);
    o1[3] = f2bf((a.w - mu) * rs * ga.w + ba.w);
    o2[0] = f2bf((c.x - mu) * rs * gc.x + bc.x);
    o2[1] = f2bf((c.y - mu) * rs * gc.y + bc.y);
    o2[2] = f2bf((c.z - mu) * rs * gc.z + bc.z);
    o2[3] = f2bf((c.w - mu) * rs * gc.w + bc.w);
    short* orow = out + (size_t)row * Cc;
    *(short4v*)&orow[l * 4]       = o1;
    *(short4v*)&orow[256 + l * 4] = o2;
}

// ---------------------------------------------------------------- layernorm: bf16 in, 1 wave/row
__global__ __launch_bounds__(256) void ln_bf(const short* __restrict__ x,
                                             const float* __restrict__ g,
                                             const float* __restrict__ b,
                                             short* __restrict__ out) {
    int z = blockIdx.y;
    x += z * SLAB; g += z * Cc; b += z * Cc; out += z * SLAB;
    int row = blockIdx.x * 4 + (threadIdx.x >> 6);
    int l = threadIdx.x & 63;
    const short* xr = x + (size_t)row * Cc;
    short8v v = *(const short8v*)&xr[l * 8];
    float xv[8];
    float s = 0.f, q = 0.f;
#pragma unroll
    for (int i = 0; i < 8; i++) {
        xv[i] = bf2f(v[i]);
        s += xv[i]; q += xv[i] * xv[i];
    }
#pragma unroll
    for (int o = 1; o < 64; o <<= 1) { s += __shfl_xor(s, o, 64); q += __shfl_xor(q, o, 64); }
    float mu = s * (1.f / Cc);
    float var = q * (1.f / Cc) - mu * mu;
    float rs = rsqrtf(var + 1e-5f);
    short8v ov;
#pragma unroll
    for (int i = 0; i < 8; i++) {
        float gg = g[l * 8 + i], bb = b[l * 8 + i];
        ov[i] = f2bf((xv[i] - mu) * rs * gg + bb);
    }
    *(short8v*)&out[(size_t)row * Cc + l * 8] = ov;
}

// ---------------------------------------------------------------- m97-style GEMM, z-batched
// RESK: 0 = no residual, 1 = f32 residual, 2 = bf16 residual
template<int BM, int BN, int ACT, bool BIAS, int RESK, bool WF, bool WB>
__global__ __launch_bounds__(256, 2) void gemm2(
    const short* __restrict__ A, int lda, long long a_zs,
    const short* __restrict__ Wt, int ldw, long long w_zs,
    const float* __restrict__ bias, long long bias_zs,
    const void* __restrict__ res, long long res_zs,
    float* __restrict__ outF, long long outF_zs,
    short* __restrict__ outB, long long outB_zs,
    int ldc, int K, float oscale) {
    constexpr int BK = 64;
    __shared__ short As[BM][BK];
    __shared__ short Bs[BN][BK];
    long long z = blockIdx.z;
    A += z * a_zs; Wt += z * w_zs;
    if (BIAS) bias += z * bias_zs;
    const float* resf = nullptr; const short* resb = nullptr;
    if constexpr (RESK == 1) resf = (const float*)res + z * res_zs;
    if constexpr (RESK == 2) resb = (const short*)res + z * res_zs;
    if (WF)   outF += z * outF_zs;
    if (WB)   outB += z * outB_zs;
    int m0 = blockIdx.x * BM, n0 = blockIdx.y * BN;
    int tid = threadIdx.x, wv = tid >> 6, l = tid & 63, lr = l & 15, lg = l >> 4;
    constexpr int WM = BM / 2, WN = BN / 2;
    int wm = wv & 1, wn = wv >> 1;
    constexpr int AI = WM / 16, BJ = WN / 16;
    float4v acc[AI][BJ] = {};
    int lrow = l >> 3;
    int gcol = (l & 7) ^ lrow;
    constexpr int CHA = BM / 8, CHB = BN / 8;
    for (int k0 = 0; k0 < K; k0 += BK) {
        __syncthreads();
#pragma unroll
        for (int c = 0; c < CHA / 4; c++) {
            int ch = wv + c * 4;
            gload_lds16(&A[(size_t)(m0 + ch * 8 + lrow) * lda + k0 + gcol * 8],
                        &As[ch * 8][0]);
        }
#pragma unroll
        for (int c = 0; c < CHB / 4; c++) {
            int ch = wv + c * 4;
            gload_lds16(&Wt[(size_t)(n0 + ch * 8 + lrow) * ldw + k0 + gcol * 8],
                        &Bs[ch * 8][0]);
        }
        __syncthreads();
#pragma unroll
        for (int kk = 0; kk < 2; kk++) {
            int g = (kk * 4 + lg) ^ (lr & 7);
            short8v af[AI], bfv[BJ];
#pragma unroll
            for (int i = 0; i < AI; i++)
                af[i] = *(const short8v*)&As[wm * WM + i * 16 + lr][g * 8];
#pragma unroll
            for (int j = 0; j < BJ; j++)
                bfv[j] = *(const short8v*)&Bs[wn * WN + j * 16 + lr][g * 8];
#pragma unroll
            for (int i = 0; i < AI; i++)
#pragma unroll
                for (int j = 0; j < BJ; j++)
                    acc[i][j] = mfma16(af[i], bfv[j], acc[i][j]);
        }
    }
#pragma unroll
    for (int i = 0; i < AI; i++) {
#pragma unroll
        for (int j = 0; j < BJ; j++) {
            int col = n0 + wn * WN + j * 16 + lr;
            float bv = BIAS ? bias[col] : 0.f;
#pragma unroll
            for (int r = 0; r < 4; r++) {
                int row = m0 + wm * WM + i * 16 + lg * 4 + r;
                float v = acc[i][j][r] * oscale + bv;
                if (ACT == 1) v = tanhf(v);
                if (ACT == 2) v = fmaxf(v, 0.f);
                size_t idx = (size_t)row * ldc + col;
                if (RESK == 1) v += resf[idx];
                if (RESK == 2) v += bf2f(resb[idx]);
                if (WF) outF[idx] = v;
                if (WB) outB[idx] = f2bf(v);
            }
        }
    }
}

// ---------------------------------------------------------------- gemm3: 128x128, dbuf, mfma32 (K=2048 only)
template<int ACT, bool BIAS, int RESK, bool WF, bool WB>
__global__ __launch_bounds__(256, 2) void gemm3(
    const short* __restrict__ A, int lda, long long a_zs,
    const short* __restrict__ Wt, int ldw, long long w_zs,
    const float* __restrict__ bias, long long bias_zs,
    const void* __restrict__ res, long long res_zs,
    float* __restrict__ outF, long long outF_zs,
    short* __restrict__ outB, long long outB_zs,
    int ldc, int K, float oscale) {
    constexpr int BM = 128, BN = 128, BK = 64;
    __shared__ short As[2][BM][BK];
    __shared__ short Bs[2][BN][BK];
    long long z = blockIdx.z;
    A += z * a_zs; Wt += z * w_zs;
    if (BIAS) bias += z * bias_zs;
    const float* resf = nullptr; const short* resb = nullptr;
    if constexpr (RESK == 1) resf = (const float*)res + z * res_zs;
    if constexpr (RESK == 2) resb = (const short*)res + z * res_zs;
    if (WF)   outF += z * outF_zs;
    if (WB)   outB += z * outB_zs;
    int m0 = blockIdx.x * BM, n0 = blockIdx.y * BN;
    int tid = threadIdx.x, wv = tid >> 6, l = tid & 63;
    int lq = l & 31, hi = l >> 5;
    int wm = wv & 1, wn = wv >> 1;
    f32x16 acc[2][2] = {};
    int lrow = l >> 3;
    int gcol = (l & 7) ^ lrow;

    auto STAGE = [&](int bi, int k0) {
#pragma unroll
        for (int c = 0; c < 4; c++) {
            int ch = wv + c * 4;
            gload_lds16(&A[(size_t)(m0 + ch * 8 + lrow) * lda + k0 + gcol * 8],
                        &As[bi][ch * 8][0]);
        }
#pragma unroll
        for (int c = 0; c < 4; c++) {
            int ch = wv + c * 4;
            gload_lds16(&Wt[(size_t)(n0 + ch * 8 + lrow) * ldw + k0 + gcol * 8],
                        &Bs[bi][ch * 8][0]);
        }
    };

    STAGE(0, 0);
    __syncthreads();
    int NT = K / BK;
    for (int t = 0; t < NT; t++) {
        int cur = t & 1;
        if (t + 1 < NT) STAGE(cur ^ 1, (t + 1) * BK);
        const short (*Ac)[BK] = As[cur];
        const short (*Bc)[BK] = Bs[cur];
#pragma unroll
        for (int ks = 0; ks < 4; ks++) {
            int g = (ks * 2 + hi) ^ (lq & 7);
            short8v af[2], bf[2];
#pragma unroll
            for (int i = 0; i < 2; i++)
                af[i] = *(const short8v*)&Ac[wm * 64 + i * 32 + lq][g * 8];
#pragma unroll
            for (int j = 0; j < 2; j++)
                bf[j] = *(const short8v*)&Bc[wn * 64 + j * 32 + lq][g * 8];
#pragma unroll
            for (int i = 0; i < 2; i++)
#pragma unroll
                for (int j = 0; j < 2; j++)
                    acc[i][j] = mfma32(af[i], bf[j], acc[i][j]);
        }
        __syncthreads();
    }
#pragma unroll
    for (int i = 0; i < 2; i++) {
#pragma unroll
        for (int j = 0; j < 2; j++) {
            int col = n0 + wn * 64 + j * 32 + lq;
            float bv = BIAS ? bias[col] : 0.f;
#pragma unroll
            for (int r = 0; r < 16; r++) {
                int row = m0 + wm * 64 + i * 32 + 4 * hi + (r & 3) + 8 * (r >> 2);
                float v = acc[i][j][r] * oscale + bv;
                if (ACT == 1) v = tanhf(v);
                if (ACT == 2) v = fmaxf(v, 0.f);
                size_t idx = (size_t)row * ldc + col;
                if (RESK == 1) v += resf[idx];
                if (RESK == 2) v += bf2f(resb[idx]);
                if (WF) outF[idx] = v;
                if (WB) outB[idx] = f2bf(v);
            }
        }
    }
}

// ---------------------------------------------------------------- gemm_kv: 128x128 tile = one head's K|V
__global__ __launch_bounds__(256, 2) void gemm_kv(
    const short* __restrict__ A, long long a_zs,
    const short* __restrict__ Wt, long long w_zs,
    short* __restrict__ outB, long long outB_zs,
    short* __restrict__ VTo, int K) {
    constexpr int BK = 64;
    __shared__ short As[128][BK];
    __shared__ short Bs[128][BK];
    __shared__ short Tv[64][136];
    long long z = blockIdx.z;
    A += z * a_zs; Wt += z * w_zs; outB += z * outB_zs;
    int m0 = blockIdx.x * 128, n0 = blockIdx.y * 128;
    int tid = threadIdx.x, wv = tid >> 6, l = tid & 63, lr = l & 15, lg = l >> 4;
    int wm = wv & 1, wn = wv >> 1;
    float4v acc[4][4] = {};
    int lrow = l >> 3;
    int gcol = (l & 7) ^ lrow;
    for (int k0 = 0; k0 < K; k0 += BK) {
        __syncthreads();
#pragma unroll
        for (int c = 0; c < 4; c++) {
            int ch = wv + c * 4;
            gload_lds16(&A[(size_t)(m0 + ch * 8 + lrow) * 512 + k0 + gcol * 8],
                        &As[ch * 8][0]);
        }
#pragma unroll
        for (int c = 0; c < 4; c++) {
            int ch = wv + c * 4;
            gload_lds16(&Wt[(size_t)(n0 + ch * 8 + lrow) * 512 + k0 + gcol * 8],
                        &Bs[ch * 8][0]);
        }
        __syncthreads();
#pragma unroll
        for (int kk = 0; kk < 2; kk++) {
            int g = (kk * 4 + lg) ^ (lr & 7);
            short8v af[4], bfv[4];
#pragma unroll
            for (int i = 0; i < 4; i++)
                af[i] = *(const short8v*)&As[wm * 64 + i * 16 + lr][g * 8];
#pragma unroll
            for (int j = 0; j < 4; j++)
                bfv[j] = *(const short8v*)&Bs[wn * 64 + j * 16 + lr][g * 8];
#pragma unroll
            for (int i = 0; i < 4; i++)
#pragma unroll
                for (int j = 0; j < 4; j++)
                    acc[i][j] = mfma16(af[i], bfv[j], acc[i][j]);
        }
    }
    if (wn == 0) {     // K-half: normal write, cols n0 + 0..63
#pragma unroll
        for (int i = 0; i < 4; i++)
#pragma unroll
            for (int j = 0; j < 4; j++) {
                int col = n0 + j * 16 + lr;
#pragma unroll
                for (int r = 0; r < 4; r++) {
                    int row = m0 + wm * 64 + i * 16 + lg * 4 + r;
                    outB[(size_t)row * 1024 + col] = f2bf(acc[i][j][r]);
                }
            }
    } else {           // V-half: stage transposed in LDS
#pragma unroll
        for (int i = 0; i < 4; i++)
#pragma unroll
            for (int j = 0; j < 4; j++) {
                int d = j * 16 + lr;
#pragma unroll
                for (int r = 0; r < 4; r++)
                    Tv[d][wm * 64 + i * 16 + lg * 4 + r] = f2bf(acc[i][j][r]);
            }
    }
    __syncthreads();
    int b = m0 >> 10, trow0 = m0 & 1023, h = n0 >> 7;
    short* dst = VTo + (size_t)(blockIdx.z * 64 + b * 8 + h) * 65536;
    int d = tid >> 2, c0 = (tid & 3) * 32;
#pragma unroll
    for (int q = 0; q < 4; q++)
        *(short8v*)&dst[(size_t)d * Tt + trow0 + c0 + q * 8] =
            *(const short8v*)&Tv[d][c0 + q * 8];
}

// ---------------------------------------------------------------- per-head proj2 (K=32)
__global__ __launch_bounds__(256) void proj2(const short* __restrict__ Z,
                                             const short* __restrict__ W2,
                                             short* __restrict__ Qo,
                                             short* __restrict__ Ko,
                                             short* __restrict__ VTo,
                                             float qscale) {
    __shared__ short As[64][40], Ws[64][40];
    __shared__ short Tv[64][72];
    int zz = blockIdx.y, t = zz >> 4, m = (zz >> 3) & 1, h = zz & 7;
    int m0 = blockIdx.x * 64;
    const short* Ap = Z + (size_t)m * ((size_t)ROWS * 768) + t * 256 + h * 32;
    const short* Wp = W2 + (size_t)zz * 2048;
    float sc = (t == 0) ? qscale : 1.0f;
    int tid = threadIdx.x, w = tid >> 6, l = tid & 63, lr = l & 15, lg = l >> 4;
    int r = tid >> 2, c = (tid & 3) * 8;
    *(short8v*)&As[r][c] = *(const short8v*)&Ap[(size_t)(m0 + r) * 768 + c];
    *(short8v*)&Ws[r][c] = *(const short8v*)&Wp[r * 32 + c];
    __syncthreads();
    short8v af = *(const short8v*)&As[w * 16 + lr][lg * 8];
    float4v acc[4] = {};
#pragma unroll
    for (int j = 0; j < 4; j++) {
        short8v bf = *(const short8v*)&Ws[j * 16 + lr][lg * 8];
        acc[j] = mfma16(af, bf, acc[j]);
    }
    if (t < 2) {
        short* Op = (t == 0 ? Qo : Ko) + (size_t)m * SLAB + h * 64;
#pragma unroll
        for (int j = 0; j < 4; j++)
#pragma unroll
            for (int rr = 0; rr < 4; rr++)
                Op[(size_t)(m0 + w * 16 + lg * 4 + rr) * 512 + j * 16 + lr] =
                    f2bf(acc[j][rr] * sc);
    } else {
#pragma unroll
        for (int j = 0; j < 4; j++)
#pragma unroll
            for (int rr = 0; rr < 4; rr++)
                Tv[j * 16 + lr][w * 16 + lg * 4 + rr] = f2bf(acc[j][rr]);
        __syncthreads();
        int b = m0 >> 10, trow0 = m0 & 1023;
        int z64 = m * 64 + b * 8 + h;
        short* dst = VTo + (size_t)z64 * 65536;
        int d = w * 16 + (l >> 2), toff = (l & 3) * 16;
        *(short8v*)&dst[(size_t)d * Tt + trow0 + toff]     = *(const short8v*)&Tv[d][toff];
        *(short8v*)&dst[(size_t)d * Tt + trow0 + toff + 8] = *(const short8v*)&Tv[d][toff + 8];
    }
}

// ---------------------------------------------------------------- flash attention v4
__global__ __launch_bounds__(512, 4) void flash_attn4(
    const short* __restrict__ Q, const short* __restrict__ K,
    const short* __restrict__ VT, short* __restrict__ O,
    int krs, int khs, long long qzs, long long kzs, long long vtzs, long long ozs)
{
    __shared__ short Ks[2][64][64];
    __shared__ short Vs[2][64][64];
    int id = blockIdx.x;
    int bh = id & 63, mod = (id >> 6) & 1, p = (id >> 7) & 3;
    Q += (long long)mod * qzs; K += (long long)mod * kzs;
    VT += (long long)mod * vtzs; O += (long long)mod * ozs;
    int b = bh >> 3, h = bh & 7;
    int tid = threadIdx.x, w = tid >> 6, l = tid & 63;
    int lq = l & 31, hi = l >> 5;
    int strip = (w < 4) ? p : 7 - p;
    int qwb = strip * 128 + (w & 3) * 32;
    int qabs = qwb + lq;
    const short* Qp = Q + (size_t)b * Tt * Cc + h * HSs;
    const short* Kp = K + (size_t)b * Tt * krs + h * khs;
    const short* Vp = VT + (size_t)bh * HSs * Tt;
    short* Op = O + (size_t)b * Tt * Cc + h * HSs;

    short8v qf[4];
#pragma unroll
    for (int c = 0; c < 4; c++)
        qf[c] = *(const short8v*)&Qp[(size_t)qabs * Cc + (c * 2 + hi) * 8];

    f32x16 oacc[2] = {};
    float mrun = -1e30f, lrun = 0.f;
    int nk = 2 * (7 - p) + 2;
    short8v pk, pv;

    auto LOADT = [&](int kb) {
        int r = tid >> 3, cg = (tid & 7) ^ (r & 7);
        pk = *(const short8v*)&Kp[(size_t)(kb + r) * krs + cg * 8];
        pv = *(const short8v*)&Vp[(size_t)r * Tt + kb + cg * 8];
    };
    auto STORET = [&](int bi) {
        int r = tid >> 3, cp = tid & 7;
        *(short8v*)&Ks[bi][r][cp * 8] = pk;
        *(short8v*)&Vs[bi][r][cp * 8] = pv;
    };

    LOADT(0); STORET(0); __syncthreads();

    for (int t = 0; t < nk; t++) {
        int cur = t & 1, kb = t * 64;
        bool pre = (t + 1 < nk);
        if (pre) LOADT(kb + 64);
        if (kb <= qwb + 31) {
            bool full = (kb + 63 <= qwb);
            f32x16 st[2] = {};
            __builtin_amdgcn_s_setprio(1);
#pragma unroll
            for (int kh = 0; kh < 2; kh++) {
#pragma unroll
                for (int cc = 0; cc < 4; cc++) {
                    int r = kh * 32 + lq;
                    int cp = (cc * 2 + hi) ^ (r & 7);
                    short8v af = *(const short8v*)&Ks[cur][r][cp * 8];
                    st[kh] = mfma32(af, qf[cc], st[kh]);
                }
            }
            __builtin_amdgcn_s_setprio(0);
            float pr[32];
            if (full) {
#pragma unroll
                for (int kh = 0; kh < 2; kh++)
#pragma unroll
                    for (int r = 0; r < 16; r++) pr[kh * 16 + r] = st[kh][r];
            } else {
#pragma unroll
                for (int kh = 0; kh < 2; kh++)
#pragma unroll
                    for (int r = 0; r < 16; r++) {
                        int kabs = kb + kh * 32 + (r & 3) + 8 * (r >> 2) + 4 * hi;
                        pr[kh * 16 + r] = (kabs <= qabs) ? st[kh][r] : -3.0e38f;
                    }
            }
            float t16[16];
#pragma unroll
            for (int i = 0; i < 16; i++) t16[i] = fmaxf(pr[i], pr[i + 16]);
#pragma unroll
            for (int i = 0; i < 8; i++) t16[i] = fmaxf(t16[i], t16[i + 8]);
            float mx = fmaxf(fmaxf(fmaxf(t16[0], t16[4]), fmaxf(t16[1], t16[5])),
                             fmaxf(fmaxf(t16[2], t16[6]), fmaxf(t16[3], t16[7])));
            mx = fmaxf(mx, __shfl_xor(mx, 32));
            if (!__all(mx <= mrun + 11.5f)) {
                float mn = fmaxf(mrun, mx);
                float al = EXP2F(mrun - mn);
                mrun = mn;
                lrun *= al;
#pragma unroll
                for (int dh = 0; dh < 2; dh++)
#pragma unroll
                    for (int r = 0; r < 16; r++) oacc[dh][r] *= al;
            }
#pragma unroll
            for (int i = 0; i < 32; i++) pr[i] = EXP2F(pr[i] - mrun);
            float s16[16];
#pragma unroll
            for (int i = 0; i < 16; i++) s16[i] = pr[i] + pr[i + 16];
#pragma unroll
            for (int i = 0; i < 8; i++) s16[i] = s16[i] + s16[i + 8];
            float rsum = ((s16[0] + s16[4]) + (s16[1] + s16[5])) +
                         ((s16[2] + s16[6]) + (s16[3] + s16[7]));
            rsum += __shfl_xor(rsum, 32);
            lrun += rsum;
#pragma unroll
            for (int ks = 0; ks < 4; ks++) {
                unsigned x0, x1, y0, y1;
                asm("v_cvt_pk_bf16_f32 %0, %1, %2" : "=v"(x0) : "v"(pr[ks*8+0]), "v"(pr[ks*8+1]));
                asm("v_cvt_pk_bf16_f32 %0, %1, %2" : "=v"(x1) : "v"(pr[ks*8+2]), "v"(pr[ks*8+3]));
                asm("v_cvt_pk_bf16_f32 %0, %1, %2" : "=v"(y0) : "v"(pr[ks*8+4]), "v"(pr[ks*8+5]));
                asm("v_cvt_pk_bf16_f32 %0, %1, %2" : "=v"(y1) : "v"(pr[ks*8+6]), "v"(pr[ks*8+7]));
                asm volatile("v_permlane32_swap_b32 %0, %1" : "+v"(x0), "+v"(y0));
                asm volatile("v_permlane32_swap_b32 %0, %1" : "+v"(x1), "+v"(y1));
                union { unsigned u[4]; short8v s; } uu;
                uu.u[0] = x0; uu.u[1] = x1; uu.u[2] = y0; uu.u[3] = y1;
                __builtin_amdgcn_s_setprio(1);
#pragma unroll
                for (int dh = 0; dh < 2; dh++) {
                    int r = dh * 32 + lq;
                    int cp = (ks * 2 + hi) ^ (r & 7);
                    short8v vf = *(const short8v*)&Vs[cur][r][cp * 8];
                    oacc[dh] = mfma32(vf, uu.s, oacc[dh]);
                }
                __builtin_amdgcn_s_setprio(0);
            }
        }
        if (pre) STORET(cur ^ 1);
        __syncthreads();
    }
    float inv = 1.f / lrun;
#pragma unroll
    for (int dh = 0; dh < 2; dh++)
#pragma unroll
        for (int r = 0; r < 16; r += 2) {
            unsigned wds;
            float a0 = oacc[dh][r] * inv, a1 = oacc[dh][r + 1] * inv;
            asm("v_cvt_pk_bf16_f32 %0, %1, %2" : "=v"(wds) : "v"(a0), "v"(a1));
            int d = (r & 3) + 8 * (r >> 2) + 4 * hi + dh * 32;
            *(unsigned*)&Op[(size_t)qabs * Cc + d] = wds;
        }
}

// ---------------------------------------------------------------- host
extern "C" void kernel_launch(void* const* d_in, const int* in_sizes, int n_in,
                              void* d_out, int out_size, void* d_ws, size_t ws_size,
                              hipStream_t stream) {
    (void)in_sizes; (void)n_in; (void)out_size; (void)ws_size;
    const float* X     = (const float*)d_in[0];
    const float* saKW1 = (const float*)d_in[1];
    const float* saKB1 = (const float*)d_in[2];
    const float* saKW2 = (const float*)d_in[3];
    const float* saQW1 = (const float*)d_in[4];
    const float* saQB1 = (const float*)d_in[5];
    const float* saQW2 = (const float*)d_in[6];
    const float* saVW1 = (const float*)d_in[7];
    const float* saVB1 = (const float*)d_in[8];
    const float* saVW2 = (const float*)d_in[9];
    const float* saPW1 = (const float*)d_in[10];
    const float* saPB1 = (const float*)d_in[11];
    const float* saPW2 = (const float*)d_in[12];
    const float* saPB2 = (const float*)d_in[13];
    const float* ffW1  = (const float*)d_in[14];
    const float* ffB1  = (const float*)d_in[15];
    const float* ffW2  = (const float*)d_in[16];
    const float* ffB2  = (const float*)d_in[17];
    const float* ln1g  = (const float*)d_in[18];
    const float* ln1b  = (const float*)d_in[19];
    const float* ln2g  = (const float*)d_in[20];
    const float* ln2b  = (const float*)d_in[21];
    const float* lncg  = (const float*)d_in[22];
    const float* lncb  = (const float*)d_in[23];
    const float* caQW  = (const float*)d_in[24];
    const float* caKVW = (const float*)d_in[25];
    const float* caPW1 = (const float*)d_in[26];
    const float* caPB1 = (const float*)d_in[27];
    const float* caPW2 = (const float*)d_in[28];
    const float* caPB2 = (const float*)d_in[29];
    float* OUT = (float*)d_out;

    char* ws = (char*)d_ws;
    size_t cur = 0;
    auto alloc = [&](size_t bytes) -> char* {
        char* p = ws + cur; cur += (bytes + 255) & ~(size_t)255; return p;
    };

    short* WT = (short*)alloc((size_t)7700480 * 2);
    size_t wo = 0;
    auto wslot = [&](size_t e) -> short* { short* p = WT + wo; wo += e; return p; };
    short* w_qkv1 = wslot(786432);
    short* w_qkv2 = wslot(98304);
    short* w_pw1 = wslot(262144); short* w_pw2 = wslot(262144);
    short* w_ff1 = wslot(2097152); short* w_ff2 = wslot(2097152);
    short* w_caq = wslot(524288);  short* w_cakv = wslot(1048576);
    short* w_cp1 = wslot(262144);  short* w_cp2 = wslot(262144);
    float* bqkv = (float*)alloc(2 * 768 * 4);

    short* Hb  = (short*)alloc(2 * SLAB * 2);
    short* Qb  = (short*)alloc(2 * SLAB * 2);
    short* Obf = (short*)alloc(2 * SLAB * 2);
    short* Fb  = (short*)alloc((size_t)2 * ROWS * 2048 * 2);
    short* AB  = (short*)alloc(2 * SLAB * 2);
    short* VTb = Hb;
    short* P1b = Hb;
    short* Kb = Fb + KOFF;

    // ---- one-launch weight transpose ----
    TPack tp;
    int base = 0, ti = 0;
    auto addT = [&](const float* s, short* d, int K, int N, int slices,
                    long long moff, long long hoff) {
        tp.d[ti++] = TDesc{s, d, K, N, moff, hoff, base};
        base += (K / 32) * (N / 32) * slices;
    };
    addT(saQW1, w_qkv1,          512, 32, 16, 393216, 16384);
    addT(saKW1, w_qkv1 + 131072, 512, 32, 16, 393216, 16384);
    addT(saVW1, w_qkv1 + 262144, 512, 32, 16, 393216, 16384);
    addT(saQW2, w_qkv2,          32, 64, 16, 16384, 2048);
    addT(saKW2, w_qkv2 + 32768,  32, 64, 16, 16384, 2048);
    addT(saVW2, w_qkv2 + 65536,  32, 64, 16, 16384, 2048);
    addT(saPW1, w_pw1, 512, 256, 2, 0, 131072);
    addT(saPW2, w_pw2, 256, 512, 2, 0, 131072);
    addT(ffW1,  w_ff1, 512, 2048, 2, 0, 1048576);
    addT(ffW2,  w_ff2, 2048, 512, 2, 0, 1048576);
    addT(caQW,  w_caq, 512, 64, 16, 262144, 32768);
    addT(caKVW, w_cakv, 512, 128, 16, 524288, 65536);
    addT(caPW1, w_cp1, 512, 256, 2, 0, 131072);
    addT(caPW2, w_cp2, 256, 512, 2, 0, 131072);
    transpose_all<<<dim3(base), 256, 0, stream>>>(tp);
    bias_cat3<<<2, 256, 0, stream>>>(saQB1, saKB1, saVB1, bqkv);

    // ---- self-attention + FF, both modalities batched via blockIdx.z ----
    ln_kernel<<<dim3(ROWS / 4, 2), 256, 0, stream>>>(X, ln1g, ln1b, Hb, BTC);
    gemm2<128, 128, 1, true, 0, false, true><<<dim3(64, 6, 2), 256, 0, stream>>>(
        Hb, 512, SLAB, w_qkv1, 512, 393216, bqkv, 768,
        nullptr, 0, nullptr, 0, Fb, (long long)ROWS * 768, 768, 512, 1.0f);
    proj2<<<dim3(128, 48), 256, 0, stream>>>(Fb, w_qkv2, Qb, Kb, VTb, SCQ);
    flash_attn4<<<dim3(512), 512, 0, stream>>>(
        Qb, Kb, VTb, Obf, 512, 64, SLAB, SLAB, 4194304, SLAB);
    gemm2<64, 128, 1, true, 0, false, true><<<dim3(128, 2, 2), 256, 0, stream>>>(
        Obf, 512, SLAB, w_pw1, 512, 131072, saPB1, 256,
        nullptr, 0, nullptr, 0, P1b, (long long)ROWS * 256, 256, 512, 1.0f);
    // pw2: x + sa  -> Obf (bf16 only; OUT f32 write eliminated)
    gemm2<64, 128, 0, true, 1, false, true><<<dim3(128, 4, 2), 256, 0, stream>>>(
        P1b, 256, (long long)ROWS * 256, w_pw2, 256, 131072, saPB2, 512,
        X, (long long)BTC, nullptr, 0, Obf, SLAB, 512, 256, 1.0f);
    ln_bf<<<dim3(ROWS / 4, 2), 256, 0, stream>>>(Obf, ln2g, ln2b, Hb);
    gemm2<128, 128, 2, true, 0, false, true><<<dim3(64, 16, 2), 256, 0, stream>>>(
        Hb, 512, SLAB, w_ff1, 512, 1048576, ffB1, 2048,
        nullptr, 0, nullptr, 0, Fb, (long long)ROWS * 2048, 2048, 512, 1.0f);
    // ff2: attended = ff + (x+sa, bf16 residual from Obf) -> AB (bf16 only)
    gemm3<0, true, 2, false, true><<<dim3(64, 4, 2), 256, 0, stream>>>(
        Fb, 2048, (long long)ROWS * 2048, w_ff2, 2048, 1048576, ffB2, 512,
        Obf, (long long)SLAB, nullptr, 0, AB, SLAB, 512, 2048, 1.0f);

    // ---- cross-attention, both modalities batched ----
    ln_bf<<<dim3(ROWS / 4, 2), 256, 0, stream>>>(AB, lncg, lncb, Hb);
    gemm2<64, 128, 0, false, 0, false, true><<<dim3(128, 4, 2), 256, 0, stream>>>(
        Hb, 512, SLAB, w_caq, 512, 262144, nullptr, 0,
        nullptr, 0, nullptr, 0, Qb, SLAB, 512, 512, SCQ);
    gemm_kv<<<dim3(64, 8, 2), 256, 0, stream>>>(
        AB + SLAB, -(long long)SLAB, w_cakv, 524288,
        Fb, (long long)ROWS * 1024, VTb, 512);
    flash_attn4<<<dim3(512), 512, 0, stream>>>(
        Qb, Fb, VTb, Obf, 1024, 128, SLAB, (long long)ROWS * 1024, 4194304, SLAB);
    gemm2<64, 128, 1, true, 0, false, true><<<dim3(128, 2, 2), 256, 0, stream>>>(
        Obf, 512, SLAB, w_cp1, 512, 131072, caPB1, 256,
        nullptr, 0, nullptr, 0, P1b, (long long)ROWS * 256, 256, 512, 1.0f);
    // cp2: OUT = attended (bf16 residual from AB) + ca_out   (sole OUT writer)
    gemm2<64, 128, 0, true, 2, true, false><<<dim3(128, 4, 2), 256, 0, stream>>>(
        P1b, 256, (long long)ROWS * 256, w_cp2, 256, 131072, caPB2, 512,
        AB, (long long)SLAB, OUT, BTC, nullptr, 0, 512, 256, 1.0f);
}